// Round 7
// baseline (965.754 us; speedup 1.0000x reference)
//
#include <hip/hip_runtime.h>

#define B_   128
#define DIM_ 768
#define NH_  12
#define HD_  64
#define N_   256

using short8 = __attribute__((ext_vector_type(8))) short;
using half8  = __attribute__((ext_vector_type(8))) _Float16;
using f32x4  = __attribute__((ext_vector_type(4))) float;
typedef unsigned short u16;
typedef unsigned int   u32;

// Staged (fragment-major) layout: per (tile, kstep) a 128row x 32k block is
// 512 chunks of 8 elems; chunk c = mtblock*64 + kgrp*16 + row16, where
// row = mtblock*16 + row16, k = kstep*32 + kgrp*8 + koff.
// Wave frag read for (block mtb): chunk = mtb*64 + lane  -> lane-linear.

__device__ __forceinline__ u16 f2bf_hi(float f) {
    union { float f; u32 u; } v; v.f = f;
    u32 r = (v.u + 0x7fffu + ((v.u >> 16) & 1u)) >> 16;   // RNE
    return (u16)r;
}
__device__ __forceinline__ float bf2f(u16 h) {
    union { u32 u; float f; } v; v.u = ((u32)h) << 16;
    return v.f;
}

// ---------------------------------------------------------------------------
// bias = face_prior[h,n,m] + rel_table[relidx(n,m), h]   -> [NH, N, N]
// ---------------------------------------------------------------------------
__global__ __launch_bounds__(256) void bias_kernel(
    const float* __restrict__ face_prior, const float* __restrict__ rel_table,
    float* __restrict__ bias)
{
    int idx = blockIdx.x * 256 + threadIdx.x;
    int m = idx & 255;
    int n = (idx >> 8) & 255;
    int h = idx >> 16;
    int rn = n >> 4, cn = n & 15;
    int rm = m >> 4, cm = m & 15;
    int ridx = (rn - rm + 15) * 31 + (cn - cm + 15);
    bias[idx] = face_prior[idx] + rel_table[ridx * NH_ + h];
}

// ---------------------------------------------------------------------------
// qkv_w fp32 [2304][768] -> hi/lo bf16 in staged layout [18][24][512][8]
// one thread per chunk; writes linear, reads L2-cached.
// ---------------------------------------------------------------------------
__global__ __launch_bounds__(256) void split_w_staged(
    const float* __restrict__ in, u16* __restrict__ hi, u16* __restrict__ lo,
    int nchunk)
{
    int gid = blockIdx.x * 256 + threadIdx.x;
    if (gid >= nchunk) return;
    int t   = gid / 12288;          // 24*512
    int rem = gid % 12288;
    int ks  = rem >> 9;
    int c   = rem & 511;
    int mtb = c >> 6, kgrp = (c >> 4) & 3, r16 = c & 15;
    int srow = t * 128 + mtb * 16 + r16;
    int sk   = ks * 32 + kgrp * 8;
    float4 a = *(const float4*)(in + (size_t)srow * DIM_ + sk);
    float4 b = *(const float4*)(in + (size_t)srow * DIM_ + sk + 4);
    float v[8] = {a.x, a.y, a.z, a.w, b.x, b.y, b.z, b.w};
    union { u16 s[8]; uint4 q; } H, L;
    #pragma unroll
    for (int j = 0; j < 8; ++j) {
        u16 h = f2bf_hi(v[j]);
        H.s[j] = h;
        L.s[j] = f2bf_hi(v[j] - bf2f(h));
    }
    *(uint4*)(hi + (size_t)gid * 8) = H.q;
    *(uint4*)(lo + (size_t)gid * 8) = L.q;
}

// proj_w fp32 [768][768] -> fp16 staged [6][24][512][8]
__global__ __launch_bounds__(256) void conv_w_f16_staged(
    const float* __restrict__ in, _Float16* __restrict__ o16, int nchunk)
{
    int gid = blockIdx.x * 256 + threadIdx.x;
    if (gid >= nchunk) return;
    int t   = gid / 12288;
    int rem = gid % 12288;
    int ks  = rem >> 9;
    int c   = rem & 511;
    int mtb = c >> 6, kgrp = (c >> 4) & 3, r16 = c & 15;
    int srow = t * 128 + mtb * 16 + r16;
    int sk   = ks * 32 + kgrp * 8;
    float4 a = *(const float4*)(in + (size_t)srow * DIM_ + sk);
    float4 b = *(const float4*)(in + (size_t)srow * DIM_ + sk + 4);
    float v[8] = {a.x, a.y, a.z, a.w, b.x, b.y, b.z, b.w};
    union { _Float16 s[8]; uint4 q; } H;
    #pragma unroll
    for (int j = 0; j < 8; ++j) H.s[j] = (_Float16)v[j];
    *(uint4*)(o16 + (size_t)gid * 8) = H.q;
}

// ---------------------------------------------------------------------------
// x [B,768(k),256(n)] fp32 -> hi/lo bf16 staged [B][2][24][512][8]
// (row = n within half, k-major staged for qkv_gemm X-side)
// ---------------------------------------------------------------------------
__global__ __launch_bounds__(256) void split_transpose_x(
    const float* __restrict__ x, u16* __restrict__ hi, u16* __restrict__ lo)
{
    __shared__ float T[64][65];
    const int b = blockIdx.z, k0 = blockIdx.x * 64, n0 = blockIdx.y * 64;
    const int t = threadIdx.x;
    const float* xb = x + (size_t)b * DIM_ * N_;
    {
        int nn = t & 63, kg = t >> 6;
        #pragma unroll
        for (int r = 0; r < 16; ++r) {
            int kk = r * 4 + kg;
            T[kk][nn] = xb[(size_t)(k0 + kk) * N_ + n0 + nn];
        }
    }
    __syncthreads();
    {
        int kk2 = (t & 31) * 2, ng = t >> 5;
        #pragma unroll
        for (int r = 0; r < 8; ++r) {
            int nn = r * 8 + ng;
            float v0 = T[kk2][nn], v1 = T[kk2 + 1][nn];
            u16 h0 = f2bf_hi(v0), h1 = f2bf_hi(v1);
            u16 l0 = f2bf_hi(v0 - bf2f(h0)), l1 = f2bf_hi(v1 - bf2f(h1));
            int n = n0 + nn, k = k0 + kk2;
            int half = n >> 7, mtb = (n >> 4) & 7, r16 = n & 15;
            int ks = k >> 5, kgrp = (k >> 3) & 3, koff = k & 7;
            size_t o = ((((size_t)b * 2 + half) * 24 + ks) * 512
                        + mtb * 64 + kgrp * 16 + r16) * 8 + koff;
            *(u32*)(hi + o) = (u32)h0 | ((u32)h1 << 16);
            *(u32*)(lo + o) = (u32)l0 | ((u32)l1 << 16);
        }
    }
}

// ---------------------------------------------------------------------------
// QKV GEMM, split-bf16 MFMA, staged layout: linear staging, lane-linear LDS.
// q/k tiles (by<12): 3-term. v tiles (by>=12): 1-term, half staging.
// grid (cb*2, 18)
// ---------------------------------------------------------------------------
__global__ __launch_bounds__(256) void qkv_gemm(
    const u16* __restrict__ wh, const u16* __restrict__ wl,
    const u16* __restrict__ xh, const u16* __restrict__ xl,
    const float* __restrict__ bvec,
    u16* __restrict__ qh, u16* __restrict__ ql,
    u16* __restrict__ kh, u16* __restrict__ kl, u16* __restrict__ vv,
    int b0, int cb)
{
    __shared__ __align__(16) u16 S0[4096], S1[4096], S2[4096], S3[4096];

    const int tid  = threadIdx.x;
    const int lane = tid & 63;
    const int wv   = tid >> 6;
    const int wr   = wv >> 1;
    const int wc   = wv & 1;
    const int bx = blockIdx.x, by = blockIdx.y;
    const int bl = bx >> 1, half = bx & 1;
    const int b  = b0 + bl;
    const bool vblk = (by >= 12);

    const size_t wq0 = (size_t)by * 24 * 4096;
    const size_t xq0 = ((size_t)b * 2 + half) * 24 * 4096;

    f32x4 acc[4][4];
    #pragma unroll
    for (int i = 0; i < 4; ++i)
        #pragma unroll
        for (int j = 0; j < 4; ++j)
            acc[i][j] = (f32x4){0.f, 0.f, 0.f, 0.f};

    for (int ks = 0; ks < 24; ++ks) {
        const size_t wq = wq0 + (size_t)ks * 4096;
        const size_t xq = xq0 + (size_t)ks * 4096;
        #pragma unroll
        for (int s = 0; s < 2; ++s) {
            int c = tid + s * 256;
            *(uint4*)&S0[c * 8] = *(const uint4*)(wh + wq + c * 8);
            *(uint4*)&S2[c * 8] = *(const uint4*)(xh + xq + c * 8);
            if (!vblk) {
                *(uint4*)&S1[c * 8] = *(const uint4*)(wl + wq + c * 8);
                *(uint4*)&S3[c * 8] = *(const uint4*)(xl + xq + c * 8);
            }
        }
        __syncthreads();

        short8 ah[4], al[4];
        #pragma unroll
        for (int mt = 0; mt < 4; ++mt) {
            int ch = ((wr * 4 + mt) * 64 + lane) * 8;
            ah[mt] = *(const short8*)&S0[ch];
            if (!vblk) al[mt] = *(const short8*)&S1[ch];
        }
        #pragma unroll
        for (int nt = 0; nt < 4; ++nt) {
            int ch = ((wc * 4 + nt) * 64 + lane) * 8;
            short8 bh = *(const short8*)&S2[ch];
            if (!vblk) {
                short8 bo = *(const short8*)&S3[ch];
                #pragma unroll
                for (int mt = 0; mt < 4; ++mt) {
                    acc[mt][nt] = __builtin_amdgcn_mfma_f32_16x16x32_bf16(ah[mt], bh, acc[mt][nt], 0, 0, 0);
                    acc[mt][nt] = __builtin_amdgcn_mfma_f32_16x16x32_bf16(ah[mt], bo, acc[mt][nt], 0, 0, 0);
                    acc[mt][nt] = __builtin_amdgcn_mfma_f32_16x16x32_bf16(al[mt], bh, acc[mt][nt], 0, 0, 0);
                }
            } else {
                #pragma unroll
                for (int mt = 0; mt < 4; ++mt)
                    acc[mt][nt] = __builtin_amdgcn_mfma_f32_16x16x32_bf16(ah[mt], bh, acc[mt][nt], 0, 0, 0);
            }
        }
        __syncthreads();
    }

    // C/D layout: col = lane&15 (n), row = (lane>>4)*4 + reg (oc)
    const int ocb = by * 128 + wr * 64 + (lane >> 4) * 4;
    const int nb  = half * 128 + wc * 64 + (lane & 15);

    #pragma unroll
    for (int mt = 0; mt < 4; ++mt) {
        int oc = ocb + mt * 16;
        float4 bv = *(const float4*)(bvec + oc);
        int which = oc / DIM_;
        int r = oc - which * DIM_;
        int hh = r >> 6, d = r & 63;
        size_t rowbase = ((size_t)bl * NH_ + hh) * (N_ * HD_) + d;
        #pragma unroll
        for (int nt = 0; nt < 4; ++nt) {
            int n = nb + nt * 16;
            size_t idx = rowbase + (size_t)n * HD_;
            float v0 = acc[mt][nt][0] + bv.x;
            float v1 = acc[mt][nt][1] + bv.y;
            float v2 = acc[mt][nt][2] + bv.z;
            float v3 = acc[mt][nt][3] + bv.w;
            union { u16 s[4]; uint2 u; } H;
            H.s[0] = f2bf_hi(v0); H.s[1] = f2bf_hi(v1);
            H.s[2] = f2bf_hi(v2); H.s[3] = f2bf_hi(v3);
            if (which == 2) {
                *(uint2*)(vv + idx) = H.u;
            } else {
                union { u16 s[4]; uint2 u; } L;
                L.s[0] = f2bf_hi(v0 - bf2f(H.s[0]));
                L.s[1] = f2bf_hi(v1 - bf2f(H.s[1]));
                L.s[2] = f2bf_hi(v2 - bf2f(H.s[2]));
                L.s[3] = f2bf_hi(v3 - bf2f(H.s[3]));
                u16* ph = (which == 0) ? qh : kh;
                u16* pl = (which == 0) ? ql : kl;
                *(uint2*)(ph + idx) = H.u;
                *(uint2*)(pl + idx) = L.u;
            }
        }
    }
}

// ---------------------------------------------------------------------------
// MFMA attention, flash-chunked (2 x 128 kk, online softmax), 4 waves.
// LDS 52KB -> 3 blocks/CU. Emits ao fp16 in staged layout for proj_gemm.
// ---------------------------------------------------------------------------
__global__ __launch_bounds__(256, 3) void attn_mfma(
    const u16* __restrict__ qh, const u16* __restrict__ ql,
    const u16* __restrict__ kh, const u16* __restrict__ kl,
    const u16* __restrict__ vv,
    const float* __restrict__ bias, const float* __restrict__ fpri,
    _Float16* __restrict__ ao,
    int b0, int cb)
{
    extern __shared__ u16 lds[];
    u16* KhL = lds;            // [128][64], idx = r*64 + (kc ^ ((r&7)<<3))
    u16* KlL = lds + 8192;
    u16* VtL = lds + 16384;    // [64][128], idx = d*128 + (kk ^ ((d&7)<<3))
    const int tid  = threadIdx.x;
    const int lane = tid & 63;
    const int wv   = tid >> 6;                 // 0..3
    u16* PL = lds + 24576 + wv * 512;          // [16][32] per wave

    const int bh = blockIdx.x;
    const int bl = bh / NH_, h = bh % NH_;
    const int b  = b0 + bl;
    const size_t base = ((size_t)bl * NH_ + h) * (size_t)(N_ * HD_);

    const int l15 = lane & 15;
    const int lg  = lane >> 4;
    const int e   = (l15 & 3) << 1;            // PL swizzle

    float mrun[4], lrun[4];
    f32x4 oacc[4][4];
    #pragma unroll
    for (int qt = 0; qt < 4; ++qt) {
        mrun[qt] = -1e30f; lrun[qt] = 0.f;
        #pragma unroll
        for (int dt = 0; dt < 4; ++dt) oacc[qt][dt] = (f32x4){0.f, 0.f, 0.f, 0.f};
    }

    for (int ch = 0; ch < 2; ++ch) {
        __syncthreads();
        #pragma unroll
        for (int s = 0; s < 4; ++s) {
            int idx = tid + s * 256;
            int r = idx >> 3, kc = (idx & 7) * 8;
            int di = r * 64 + (kc ^ ((r & 7) << 3));
            size_t src = base + (size_t)(ch * 128 + r) * 64 + kc;
            *(short8*)&KhL[di] = *(const short8*)(kh + src);
            *(short8*)&KlL[di] = *(const short8*)(kl + src);
        }
        #pragma unroll
        for (int s = 0; s < 4; ++s) {
            int idx = tid + s * 256;
            int d = idx & 63, kkc = (idx >> 6) * 8;
            union { u16 s[8]; short8 v; } t;
            #pragma unroll
            for (int j = 0; j < 8; ++j)
                t.s[j] = vv[base + (size_t)(ch * 128 + kkc + j) * 64 + d];
            *(short8*)&VtL[d * 128 + (kkc ^ ((d & 7) << 3))] = t.v;
        }
        __syncthreads();

        for (int qt = 0; qt < 4; ++qt) {
            const int qg = wv * 64 + qt * 16 + l15;
            const size_t qrow = base + (size_t)qg * 64;
            short8 bqh[2], bql[2];
            #pragma unroll
            for (int c = 0; c < 2; ++c) {
                bqh[c] = *(const short8*)(qh + qrow + lg * 8 + c * 32);
                bql[c] = *(const short8*)(ql + qrow + lg * 8 + c * 32);
            }

            f32x4 sacc[8];
            const float* brow = bias + ((size_t)h * N_ + qg) * N_ + ch * 128;
            const float* frow = fpri + ((size_t)b * N_ + qg) * N_ + ch * 128;
            #pragma unroll
            for (int kt = 0; kt < 8; ++kt) {
                f32x4 sa = (f32x4){0.f, 0.f, 0.f, 0.f};
                int kr = kt * 16 + l15;
                #pragma unroll
                for (int c = 0; c < 2; ++c) {
                    int kc = lg * 8 + c * 32;
                    int di = kr * 64 + (kc ^ ((kr & 7) << 3));
                    short8 ah = *(const short8*)&KhL[di];
                    short8 al = *(const short8*)&KlL[di];
                    sa = __builtin_amdgcn_mfma_f32_16x16x32_bf16(ah, bqh[c], sa, 0, 0, 0);
                    sa = __builtin_amdgcn_mfma_f32_16x16x32_bf16(ah, bql[c], sa, 0, 0, 0);
                    sa = __builtin_amdgcn_mfma_f32_16x16x32_bf16(al, bqh[c], sa, 0, 0, 0);
                }
                float4 bs = *(const float4*)(brow + kt * 16 + lg * 4);
                float4 fs = *(const float4*)(frow + kt * 16 + lg * 4);
                sacc[kt][0] = (sa[0] * 0.125f + bs.x) * fs.x;
                sacc[kt][1] = (sa[1] * 0.125f + bs.y) * fs.y;
                sacc[kt][2] = (sa[2] * 0.125f + bs.z) * fs.z;
                sacc[kt][3] = (sa[3] * 0.125f + bs.w) * fs.w;
            }

            float cmax = -1e30f;
            #pragma unroll
            for (int kt = 0; kt < 8; ++kt)
                cmax = fmaxf(cmax, fmaxf(fmaxf(sacc[kt][0], sacc[kt][1]),
                                         fmaxf(sacc[kt][2], sacc[kt][3])));
            cmax = fmaxf(cmax, __shfl_xor(cmax, 16));
            cmax = fmaxf(cmax, __shfl_xor(cmax, 32));
            float mnew = fmaxf(mrun[qt], cmax);
            float corr = __expf(mrun[qt] - mnew);
            mrun[qt] = mnew;
            float csum = 0.f;
            #pragma unroll
            for (int kt = 0; kt < 8; ++kt) {
                #pragma unroll
                for (int j = 0; j < 4; ++j) {
                    float p = __expf(sacc[kt][j] - mnew);
                    sacc[kt][j] = p;
                    csum += p;
                }
            }
            csum += __shfl_xor(csum, 16);
            csum += __shfl_xor(csum, 32);
            lrun[qt] = lrun[qt] * corr + csum;
            #pragma unroll
            for (int dt = 0; dt < 4; ++dt) {
                oacc[qt][dt][0] *= corr; oacc[qt][dt][1] *= corr;
                oacc[qt][dt][2] *= corr; oacc[qt][dt][3] *= corr;
            }

            #pragma unroll
            for (int c2 = 0; c2 < 4; ++c2) {
                #pragma unroll
                for (int t = 0; t < 2; ++t) {
                    int kt = c2 * 2 + t;
                    union { u16 s[4]; uint2 u; } pw;
                    pw.s[0] = f2bf_hi(sacc[kt][0]);
                    pw.s[1] = f2bf_hi(sacc[kt][1]);
                    pw.s[2] = f2bf_hi(sacc[kt][2]);
                    pw.s[3] = f2bf_hi(sacc[kt][3]);
                    int u = (4 * t + lg) ^ e;
                    *(uint2*)&PL[l15 * 32 + u * 4] = pw.u;
                }
                short8 bp = *(const short8*)&PL[l15 * 32 + ((2 * lg) ^ e) * 4];
                int kc2 = lg * 8 + c2 * 32;
                #pragma unroll
                for (int dt = 0; dt < 4; ++dt) {
                    int dr = dt * 16 + l15;
                    short8 av = *(const short8*)&VtL[dr * 128 + (kc2 ^ ((dr & 7) << 3))];
                    oacc[qt][dt] = __builtin_amdgcn_mfma_f32_16x16x32_bf16(av, bp, oacc[qt][dt], 0, 0, 0);
                }
            }
        }
    }

    // epilogue: scale by 1/l, emit fp16 in staged layout [bl][2][24][512][8]
    #pragma unroll
    for (int qt = 0; qt < 4; ++qt) {
        const int qg = wv * 64 + qt * 16 + l15;
        float inv = 1.f / lrun[qt];
        const int hf  = qg >> 7, mtb = (qg >> 4) & 7, r16 = qg & 15;
        #pragma unroll
        for (int dt = 0; dt < 4; ++dt) {
            int k = h * 64 + dt * 16 + lg * 4;
            int ks = k >> 5, kgrp = (k >> 3) & 3, koff = k & 7;
            size_t off = ((((size_t)(bl * 2 + hf) * 24 + ks) * 512)
                          + mtb * 64 + kgrp * 16 + r16) * 8 + koff;
            union { _Float16 s[4]; uint2 u; } H;
            #pragma unroll
            for (int j = 0; j < 4; ++j)
                H.s[j] = (_Float16)(oacc[qt][dt][j] * inv);
            *(uint2*)(ao + off) = H.u;
        }
    }
}

// ---------------------------------------------------------------------------
// Proj GEMM, fp16 1-term, staged layout both sides. grid (cb*2, 6)
// ---------------------------------------------------------------------------
__global__ __launch_bounds__(256) void proj_gemm(
    const _Float16* __restrict__ wst, const _Float16* __restrict__ ao,
    const float* __restrict__ bvec, float* __restrict__ outp,
    int b0)
{
    __shared__ __align__(16) _Float16 SW[4096], SX[4096];

    const int tid  = threadIdx.x;
    const int lane = tid & 63;
    const int wv   = tid >> 6;
    const int wr   = wv >> 1;
    const int wc   = wv & 1;
    const int bx = blockIdx.x, by = blockIdx.y;
    const int bl = bx >> 1, half = bx & 1;
    const int b  = b0 + bl;

    const size_t wq0 = (size_t)by * 24 * 4096;
    const size_t xq0 = ((size_t)bl * 2 + half) * 24 * 4096;

    f32x4 acc[4][4];
    #pragma unroll
    for (int i = 0; i < 4; ++i)
        #pragma unroll
        for (int j = 0; j < 4; ++j)
            acc[i][j] = (f32x4){0.f, 0.f, 0.f, 0.f};

    for (int ks = 0; ks < 24; ++ks) {
        #pragma unroll
        for (int s = 0; s < 2; ++s) {
            int c = tid + s * 256;
            *(uint4*)&SW[c * 8] = *(const uint4*)(wst + wq0 + (size_t)ks * 4096 + c * 8);
            *(uint4*)&SX[c * 8] = *(const uint4*)(ao  + xq0 + (size_t)ks * 4096 + c * 8);
        }
        __syncthreads();

        half8 ah[4];
        #pragma unroll
        for (int mt = 0; mt < 4; ++mt)
            ah[mt] = *(const half8*)&SW[((wr * 4 + mt) * 64 + lane) * 8];
        #pragma unroll
        for (int nt = 0; nt < 4; ++nt) {
            half8 bh = *(const half8*)&SX[((wc * 4 + nt) * 64 + lane) * 8];
            #pragma unroll
            for (int mt = 0; mt < 4; ++mt)
                acc[mt][nt] = __builtin_amdgcn_mfma_f32_16x16x32_f16(ah[mt], bh, acc[mt][nt], 0, 0, 0);
        }
        __syncthreads();
    }

    const int ocb = by * 128 + wr * 64 + (lane >> 4) * 4;
    const int nb  = half * 128 + wc * 64 + (lane & 15);

    #pragma unroll
    for (int mt = 0; mt < 4; ++mt) {
        int oc = ocb + mt * 16;
        float4 bv = *(const float4*)(bvec + oc);
        float* obase = outp + (size_t)b * DIM_ * N_ + (size_t)oc * N_;
        #pragma unroll
        for (int nt = 0; nt < 4; ++nt) {
            int n = nb + nt * 16;
            obase[0 * N_ + n] = acc[mt][nt][0] + bv.x;
            obase[1 * N_ + n] = acc[mt][nt][1] + bv.y;
            obase[2 * N_ + n] = acc[mt][nt][2] + bv.z;
            obase[3 * N_ + n] = acc[mt][nt][3] + bv.w;
        }
    }
}

// ---------------------------------------------------------------------------
extern "C" void kernel_launch(void* const* d_in, const int* in_sizes, int n_in,
                              void* d_out, int out_size, void* d_ws, size_t ws_size,
                              hipStream_t stream)
{
    const float* x           = (const float*)d_in[0];
    const float* face_priors = (const float*)d_in[1];
    const float* qkv_w       = (const float*)d_in[2];
    const float* qkv_b       = (const float*)d_in[3];
    const float* rel_table   = (const float*)d_in[4];
    const float* face_prior  = (const float*)d_in[5];
    const float* proj_w      = (const float*)d_in[6];
    const float* proj_b      = (const float*)d_in[7];
    float* out = (float*)d_out;

    // persistent: bias 3.15MB | x staged 100.7MB | qkv_w staged 7.08MB | pw16 1.18MB
    float* ws   = (float*)d_ws;
    float* bias = ws;
    u16* xah = (u16*)(bias + 786432);
    u16* xal = xah + (size_t)B_ * N_ * DIM_;
    u16* qwh = xal + (size_t)B_ * N_ * DIM_;
    u16* qwl = qwh + (size_t)3 * DIM_ * DIM_;
    _Float16* pw16 = (_Float16*)(qwl + (size_t)3 * DIM_ * DIM_);
    u16* cbase = (u16*)(pw16 + (size_t)DIM_ * DIM_);

    // per-batch chunk: qh/ql/kh/kl/vv (bf16) + ao (fp16) = 6 * 393216 B
    int CB = 1;
    const int cands[] = {128, 64, 32, 16, 8, 4, 2, 1};
    for (int ci = 0; ci < 8; ++ci) {
        if (112066560ull + (size_t)cands[ci] * 2359296ull <= ws_size) { CB = cands[ci]; break; }
    }
    const size_t SL = (size_t)CB * NH_ * N_ * HD_;
    u16* qhb = cbase;
    u16* qlb = qhb + SL;
    u16* khb = qlb + SL;
    u16* klb = khb + SL;
    u16* vvb = klb + SL;
    _Float16* aob = (_Float16*)(vvb + SL);

    hipFuncSetAttribute((const void*)attn_mfma,
                        hipFuncAttributeMaxDynamicSharedMemorySize, 53248);

    bias_kernel<<<(NH_ * N_ * N_) / 256, 256, 0, stream>>>(face_prior, rel_table, bias);
    split_w_staged<<<(18 * 24 * 512 + 255) / 256, 256, 0, stream>>>(qkv_w, qwh, qwl, 18 * 24 * 512);
    conv_w_f16_staged<<<(6 * 24 * 512 + 255) / 256, 256, 0, stream>>>(proj_w, pw16, 6 * 24 * 512);
    split_transpose_x<<<dim3(12, 4, B_), 256, 0, stream>>>(x, xah, xal);

    for (int b0 = 0; b0 < B_; b0 += CB) {
        qkv_gemm<<<dim3(CB * 2, 18), 256, 0, stream>>>(
            qwh, qwl, xah, xal, qkv_b, qhb, qlb, khb, klb, vvb, b0, CB);

        attn_mfma<<<CB * NH_, 256, 53248, stream>>>(
            qhb, qlb, khb, klb, vvb, bias, face_priors, aob, b0, CB);

        proj_gemm<<<dim3(CB * 2, 6), 256, 0, stream>>>(
            pw16, aob, proj_b, out, b0);
    }
}

// Round 8
// 827.401 us; speedup vs baseline: 1.1672x; 1.1672x over previous
//
#include <hip/hip_runtime.h>

#define B_   128
#define DIM_ 768
#define NH_  12
#define HD_  64
#define N_   256

using short8 = __attribute__((ext_vector_type(8))) short;
using half8  = __attribute__((ext_vector_type(8))) _Float16;
using f32x4  = __attribute__((ext_vector_type(4))) float;
typedef unsigned short u16;
typedef unsigned int   u32;

// Staged (fragment-major) layout: per (tile, kstep) a 128row x 32k block is
// 512 chunks of 8 elems; chunk c = mtblock*64 + kgrp*16 + row16, where
// row = mtblock*16 + row16, k = kstep*32 + kgrp*8 + koff.
// Wave frag read for block mtb: chunk = mtb*64 + lane -> lane-linear, and
// staging chunk c = tid + s*256 -> global src AND LDS dst both lane-linear,
// which is exactly global_load_lds's required (uniform base + lane*16) form.

__device__ __forceinline__ u16 f2bf_hi(float f) {
    union { float f; u32 u; } v; v.f = f;
    u32 r = (v.u + 0x7fffu + ((v.u >> 16) & 1u)) >> 16;   // RNE
    return (u16)r;
}
__device__ __forceinline__ float bf2f(u16 h) {
    union { u32 u; float f; } v; v.u = ((u32)h) << 16;
    return v.f;
}

#define GLDS16(srcp, dstp) \
    __builtin_amdgcn_global_load_lds( \
        (const __attribute__((address_space(1))) void*)(srcp), \
        (__attribute__((address_space(3))) void*)(dstp), 16, 0, 0)

// ---------------------------------------------------------------------------
// bias = face_prior[h,n,m] + rel_table[relidx(n,m), h]   -> [NH, N, N]
// ---------------------------------------------------------------------------
__global__ __launch_bounds__(256) void bias_kernel(
    const float* __restrict__ face_prior, const float* __restrict__ rel_table,
    float* __restrict__ bias)
{
    int idx = blockIdx.x * 256 + threadIdx.x;
    int m = idx & 255;
    int n = (idx >> 8) & 255;
    int h = idx >> 16;
    int rn = n >> 4, cn = n & 15;
    int rm = m >> 4, cm = m & 15;
    int ridx = (rn - rm + 15) * 31 + (cn - cm + 15);
    bias[idx] = face_prior[idx] + rel_table[ridx * NH_ + h];
}

// ---------------------------------------------------------------------------
// qkv_w fp32 [2304][768] -> hi/lo bf16 staged [18][24][512][8]
// ---------------------------------------------------------------------------
__global__ __launch_bounds__(256) void split_w_staged(
    const float* __restrict__ in, u16* __restrict__ hi, u16* __restrict__ lo,
    int nchunk)
{
    int gid = blockIdx.x * 256 + threadIdx.x;
    if (gid >= nchunk) return;
    int t   = gid / 12288;          // 24*512
    int rem = gid % 12288;
    int ks  = rem >> 9;
    int c   = rem & 511;
    int mtb = c >> 6, kgrp = (c >> 4) & 3, r16 = c & 15;
    int srow = t * 128 + mtb * 16 + r16;
    int sk   = ks * 32 + kgrp * 8;
    float4 a = *(const float4*)(in + (size_t)srow * DIM_ + sk);
    float4 b = *(const float4*)(in + (size_t)srow * DIM_ + sk + 4);
    float v[8] = {a.x, a.y, a.z, a.w, b.x, b.y, b.z, b.w};
    union { u16 s[8]; uint4 q; } H, L;
    #pragma unroll
    for (int j = 0; j < 8; ++j) {
        u16 h = f2bf_hi(v[j]);
        H.s[j] = h;
        L.s[j] = f2bf_hi(v[j] - bf2f(h));
    }
    *(uint4*)(hi + (size_t)gid * 8) = H.q;
    *(uint4*)(lo + (size_t)gid * 8) = L.q;
}

// proj_w fp32 [768][768] -> fp16 staged [6][24][512][8]
__global__ __launch_bounds__(256) void conv_w_f16_staged(
    const float* __restrict__ in, _Float16* __restrict__ o16, int nchunk)
{
    int gid = blockIdx.x * 256 + threadIdx.x;
    if (gid >= nchunk) return;
    int t   = gid / 12288;
    int rem = gid % 12288;
    int ks  = rem >> 9;
    int c   = rem & 511;
    int mtb = c >> 6, kgrp = (c >> 4) & 3, r16 = c & 15;
    int srow = t * 128 + mtb * 16 + r16;
    int sk   = ks * 32 + kgrp * 8;
    float4 a = *(const float4*)(in + (size_t)srow * DIM_ + sk);
    float4 b = *(const float4*)(in + (size_t)srow * DIM_ + sk + 4);
    float v[8] = {a.x, a.y, a.z, a.w, b.x, b.y, b.z, b.w};
    union { _Float16 s[8]; uint4 q; } H;
    #pragma unroll
    for (int j = 0; j < 8; ++j) H.s[j] = (_Float16)v[j];
    *(uint4*)(o16 + (size_t)gid * 8) = H.q;
}

// ---------------------------------------------------------------------------
// x [B,768(k),256(n)] fp32 -> hi/lo bf16 staged [B][2][24][512][8]
// ---------------------------------------------------------------------------
__global__ __launch_bounds__(256) void split_transpose_x(
    const float* __restrict__ x, u16* __restrict__ hi, u16* __restrict__ lo)
{
    __shared__ float T[64][65];
    const int b = blockIdx.z, k0 = blockIdx.x * 64, n0 = blockIdx.y * 64;
    const int t = threadIdx.x;
    const float* xb = x + (size_t)b * DIM_ * N_;
    {
        int nn = t & 63, kg = t >> 6;
        #pragma unroll
        for (int r = 0; r < 16; ++r) {
            int kk = r * 4 + kg;
            T[kk][nn] = xb[(size_t)(k0 + kk) * N_ + n0 + nn];
        }
    }
    __syncthreads();
    {
        int kk2 = (t & 31) * 2, ng = t >> 5;
        #pragma unroll
        for (int r = 0; r < 8; ++r) {
            int nn = r * 8 + ng;
            float v0 = T[kk2][nn], v1 = T[kk2 + 1][nn];
            u16 h0 = f2bf_hi(v0), h1 = f2bf_hi(v1);
            u16 l0 = f2bf_hi(v0 - bf2f(h0)), l1 = f2bf_hi(v1 - bf2f(h1));
            int n = n0 + nn, k = k0 + kk2;
            int half = n >> 7, mtb = (n >> 4) & 7, r16 = n & 15;
            int ks = k >> 5, kgrp = (k >> 3) & 3, koff = k & 7;
            size_t o = ((((size_t)b * 2 + half) * 24 + ks) * 512
                        + mtb * 64 + kgrp * 16 + r16) * 8 + koff;
            *(u32*)(hi + o) = (u32)h0 | ((u32)h1 << 16);
            *(u32*)(lo + o) = (u32)l0 | ((u32)l1 << 16);
        }
    }
}

// ---------------------------------------------------------------------------
// QKV GEMM: staged layout + global_load_lds direct staging (m97 structure).
// q/k tiles (by<12): 3-term split-bf16. v tiles (by>=12): 1-term.
// grid (cb*2, 18)
// ---------------------------------------------------------------------------
__global__ __launch_bounds__(256) void qkv_gemm(
    const u16* __restrict__ wh, const u16* __restrict__ wl,
    const u16* __restrict__ xh, const u16* __restrict__ xl,
    const float* __restrict__ bvec,
    u16* __restrict__ qh, u16* __restrict__ ql,
    u16* __restrict__ kh, u16* __restrict__ kl, u16* __restrict__ vv,
    int b0, int cb)
{
    __shared__ __align__(16) u16 S0[4096], S1[4096], S2[4096], S3[4096];

    const int tid  = threadIdx.x;
    const int lane = tid & 63;
    const int wv   = tid >> 6;
    const int wr   = wv >> 1;
    const int wc   = wv & 1;
    const int bx = blockIdx.x, by = blockIdx.y;
    const int bl = bx >> 1, half = bx & 1;
    const int b  = b0 + bl;
    const bool vblk = (by >= 12);

    const size_t wq0 = (size_t)by * 24 * 4096;
    const size_t xq0 = ((size_t)b * 2 + half) * 24 * 4096;

    f32x4 acc[4][4];
    #pragma unroll
    for (int i = 0; i < 4; ++i)
        #pragma unroll
        for (int j = 0; j < 4; ++j)
            acc[i][j] = (f32x4){0.f, 0.f, 0.f, 0.f};

    // wave-uniform LDS dest bases (u16 index): wv*512 + s*2048
    const int d0 = wv * 512;

    for (int ks = 0; ks < 24; ++ks) {
        const size_t wq = wq0 + (size_t)ks * 4096 + d0;   // + lane*8 implicit
        const size_t xq = xq0 + (size_t)ks * 4096 + d0;
        // chunk c = tid + s*256  ->  src = base + c*8, dst = c*16B
        #pragma unroll
        for (int s = 0; s < 2; ++s) {
            GLDS16(wh + wq + s * 2048 + lane * 8, &S0[d0 + s * 2048]);
            GLDS16(xh + xq + s * 2048 + lane * 8, &S2[d0 + s * 2048]);
            if (!vblk) {
                GLDS16(wl + wq + s * 2048 + lane * 8, &S1[d0 + s * 2048]);
                GLDS16(xl + xq + s * 2048 + lane * 8, &S3[d0 + s * 2048]);
            }
        }
        __syncthreads();

        short8 ah[4], al[4];
        #pragma unroll
        for (int mt = 0; mt < 4; ++mt) {
            int ch = ((wr * 4 + mt) * 64 + lane) * 8;
            ah[mt] = *(const short8*)&S0[ch];
            if (!vblk) al[mt] = *(const short8*)&S1[ch];
        }
        #pragma unroll
        for (int nt = 0; nt < 4; ++nt) {
            int ch = ((wc * 4 + nt) * 64 + lane) * 8;
            short8 bh = *(const short8*)&S2[ch];
            if (!vblk) {
                short8 bo = *(const short8*)&S3[ch];
                #pragma unroll
                for (int mt = 0; mt < 4; ++mt) {
                    acc[mt][nt] = __builtin_amdgcn_mfma_f32_16x16x32_bf16(ah[mt], bh, acc[mt][nt], 0, 0, 0);
                    acc[mt][nt] = __builtin_amdgcn_mfma_f32_16x16x32_bf16(ah[mt], bo, acc[mt][nt], 0, 0, 0);
                    acc[mt][nt] = __builtin_amdgcn_mfma_f32_16x16x32_bf16(al[mt], bh, acc[mt][nt], 0, 0, 0);
                }
            } else {
                #pragma unroll
                for (int mt = 0; mt < 4; ++mt)
                    acc[mt][nt] = __builtin_amdgcn_mfma_f32_16x16x32_bf16(ah[mt], bh, acc[mt][nt], 0, 0, 0);
            }
        }
        __syncthreads();
    }

    // C/D layout: col = lane&15 (n), row = (lane>>4)*4 + reg (oc)
    const int ocb = by * 128 + wr * 64 + (lane >> 4) * 4;
    const int nb  = half * 128 + wc * 64 + (lane & 15);

    #pragma unroll
    for (int mt = 0; mt < 4; ++mt) {
        int oc = ocb + mt * 16;
        float4 bv = *(const float4*)(bvec + oc);
        int which = oc / DIM_;
        int r = oc - which * DIM_;
        int hh = r >> 6, d = r & 63;
        size_t rowbase = ((size_t)bl * NH_ + hh) * (N_ * HD_) + d;
        #pragma unroll
        for (int nt = 0; nt < 4; ++nt) {
            int n = nb + nt * 16;
            size_t idx = rowbase + (size_t)n * HD_;
            float v0 = acc[mt][nt][0] + bv.x;
            float v1 = acc[mt][nt][1] + bv.y;
            float v2 = acc[mt][nt][2] + bv.z;
            float v3 = acc[mt][nt][3] + bv.w;
            union { u16 s[4]; uint2 u; } H;
            H.s[0] = f2bf_hi(v0); H.s[1] = f2bf_hi(v1);
            H.s[2] = f2bf_hi(v2); H.s[3] = f2bf_hi(v3);
            if (which == 2) {
                *(uint2*)(vv + idx) = H.u;
            } else {
                union { u16 s[4]; uint2 u; } L;
                L.s[0] = f2bf_hi(v0 - bf2f(H.s[0]));
                L.s[1] = f2bf_hi(v1 - bf2f(H.s[1]));
                L.s[2] = f2bf_hi(v2 - bf2f(H.s[2]));
                L.s[3] = f2bf_hi(v3 - bf2f(H.s[3]));
                u16* ph = (which == 0) ? qh : kh;
                u16* pl = (which == 0) ? ql : kl;
                *(uint2*)(ph + idx) = H.u;
                *(uint2*)(pl + idx) = L.u;
            }
        }
    }
}

// ---------------------------------------------------------------------------
// MFMA attention, flash-chunked (2 x 128 kk, online softmax), 4 waves.
// LDS 52KB -> 3 blocks/CU. Emits ao fp16 in staged layout for proj_gemm.
// (unchanged from r7)
// ---------------------------------------------------------------------------
__global__ __launch_bounds__(256, 3) void attn_mfma(
    const u16* __restrict__ qh, const u16* __restrict__ ql,
    const u16* __restrict__ kh, const u16* __restrict__ kl,
    const u16* __restrict__ vv,
    const float* __restrict__ bias, const float* __restrict__ fpri,
    _Float16* __restrict__ ao,
    int b0, int cb)
{
    extern __shared__ u16 lds[];
    u16* KhL = lds;            // [128][64], idx = r*64 + (kc ^ ((r&7)<<3))
    u16* KlL = lds + 8192;
    u16* VtL = lds + 16384;    // [64][128], idx = d*128 + (kk ^ ((d&7)<<3))
    const int tid  = threadIdx.x;
    const int lane = tid & 63;
    const int wv   = tid >> 6;                 // 0..3
    u16* PL = lds + 24576 + wv * 512;          // [16][32] per wave

    const int bh = blockIdx.x;
    const int bl = bh / NH_, h = bh % NH_;
    const int b  = b0 + bl;
    const size_t base = ((size_t)bl * NH_ + h) * (size_t)(N_ * HD_);

    const int l15 = lane & 15;
    const int lg  = lane >> 4;
    const int e   = (l15 & 3) << 1;            // PL swizzle

    float mrun[4], lrun[4];
    f32x4 oacc[4][4];
    #pragma unroll
    for (int qt = 0; qt < 4; ++qt) {
        mrun[qt] = -1e30f; lrun[qt] = 0.f;
        #pragma unroll
        for (int dt = 0; dt < 4; ++dt) oacc[qt][dt] = (f32x4){0.f, 0.f, 0.f, 0.f};
    }

    for (int ch = 0; ch < 2; ++ch) {
        __syncthreads();
        #pragma unroll
        for (int s = 0; s < 4; ++s) {
            int idx = tid + s * 256;
            int r = idx >> 3, kc = (idx & 7) * 8;
            int di = r * 64 + (kc ^ ((r & 7) << 3));
            size_t src = base + (size_t)(ch * 128 + r) * 64 + kc;
            *(short8*)&KhL[di] = *(const short8*)(kh + src);
            *(short8*)&KlL[di] = *(const short8*)(kl + src);
        }
        #pragma unroll
        for (int s = 0; s < 4; ++s) {
            int idx = tid + s * 256;
            int d = idx & 63, kkc = (idx >> 6) * 8;
            union { u16 s[8]; short8 v; } t;
            #pragma unroll
            for (int j = 0; j < 8; ++j)
                t.s[j] = vv[base + (size_t)(ch * 128 + kkc + j) * 64 + d];
            *(short8*)&VtL[d * 128 + (kkc ^ ((d & 7) << 3))] = t.v;
        }
        __syncthreads();

        for (int qt = 0; qt < 4; ++qt) {
            const int qg = wv * 64 + qt * 16 + l15;
            const size_t qrow = base + (size_t)qg * 64;
            short8 bqh[2], bql[2];
            #pragma unroll
            for (int c = 0; c < 2; ++c) {
                bqh[c] = *(const short8*)(qh + qrow + lg * 8 + c * 32);
                bql[c] = *(const short8*)(ql + qrow + lg * 8 + c * 32);
            }

            f32x4 sacc[8];
            const float* brow = bias + ((size_t)h * N_ + qg) * N_ + ch * 128;
            const float* frow = fpri + ((size_t)b * N_ + qg) * N_ + ch * 128;
            #pragma unroll
            for (int kt = 0; kt < 8; ++kt) {
                f32x4 sa = (f32x4){0.f, 0.f, 0.f, 0.f};
                int kr = kt * 16 + l15;
                #pragma unroll
                for (int c = 0; c < 2; ++c) {
                    int kc = lg * 8 + c * 32;
                    int di = kr * 64 + (kc ^ ((kr & 7) << 3));
                    short8 ah = *(const short8*)&KhL[di];
                    short8 al = *(const short8*)&KlL[di];
                    sa = __builtin_amdgcn_mfma_f32_16x16x32_bf16(ah, bqh[c], sa, 0, 0, 0);
                    sa = __builtin_amdgcn_mfma_f32_16x16x32_bf16(ah, bql[c], sa, 0, 0, 0);
                    sa = __builtin_amdgcn_mfma_f32_16x16x32_bf16(al, bqh[c], sa, 0, 0, 0);
                }
                float4 bs = *(const float4*)(brow + kt * 16 + lg * 4);
                float4 fs = *(const float4*)(frow + kt * 16 + lg * 4);
                sacc[kt][0] = (sa[0] * 0.125f + bs.x) * fs.x;
                sacc[kt][1] = (sa[1] * 0.125f + bs.y) * fs.y;
                sacc[kt][2] = (sa[2] * 0.125f + bs.z) * fs.z;
                sacc[kt][3] = (sa[3] * 0.125f + bs.w) * fs.w;
            }

            float cmax = -1e30f;
            #pragma unroll
            for (int kt = 0; kt < 8; ++kt)
                cmax = fmaxf(cmax, fmaxf(fmaxf(sacc[kt][0], sacc[kt][1]),
                                         fmaxf(sacc[kt][2], sacc[kt][3])));
            cmax = fmaxf(cmax, __shfl_xor(cmax, 16));
            cmax = fmaxf(cmax, __shfl_xor(cmax, 32));
            float mnew = fmaxf(mrun[qt], cmax);
            float corr = __expf(mrun[qt] - mnew);
            mrun[qt] = mnew;
            float csum = 0.f;
            #pragma unroll
            for (int kt = 0; kt < 8; ++kt) {
                #pragma unroll
                for (int j = 0; j < 4; ++j) {
                    float p = __expf(sacc[kt][j] - mnew);
                    sacc[kt][j] = p;
                    csum += p;
                }
            }
            csum += __shfl_xor(csum, 16);
            csum += __shfl_xor(csum, 32);
            lrun[qt] = lrun[qt] * corr + csum;
            #pragma unroll
            for (int dt = 0; dt < 4; ++dt) {
                oacc[qt][dt][0] *= corr; oacc[qt][dt][1] *= corr;
                oacc[qt][dt][2] *= corr; oacc[qt][dt][3] *= corr;
            }

            #pragma unroll
            for (int c2 = 0; c2 < 4; ++c2) {
                #pragma unroll
                for (int t = 0; t < 2; ++t) {
                    int kt = c2 * 2 + t;
                    union { u16 s[4]; uint2 u; } pw;
                    pw.s[0] = f2bf_hi(sacc[kt][0]);
                    pw.s[1] = f2bf_hi(sacc[kt][1]);
                    pw.s[2] = f2bf_hi(sacc[kt][2]);
                    pw.s[3] = f2bf_hi(sacc[kt][3]);
                    int u = (4 * t + lg) ^ e;
                    *(uint2*)&PL[l15 * 32 + u * 4] = pw.u;
                }
                short8 bp = *(const short8*)&PL[l15 * 32 + ((2 * lg) ^ e) * 4];
                int kc2 = lg * 8 + c2 * 32;
                #pragma unroll
                for (int dt = 0; dt < 4; ++dt) {
                    int dr = dt * 16 + l15;
                    short8 av = *(const short8*)&VtL[dr * 128 + (kc2 ^ ((dr & 7) << 3))];
                    oacc[qt][dt] = __builtin_amdgcn_mfma_f32_16x16x32_bf16(av, bp, oacc[qt][dt], 0, 0, 0);
                }
            }
        }
    }

    // epilogue: scale by 1/l, emit fp16 in staged layout [bl][2][24][512][8]
    #pragma unroll
    for (int qt = 0; qt < 4; ++qt) {
        const int qg = wv * 64 + qt * 16 + l15;
        float inv = 1.f / lrun[qt];
        const int hf  = qg >> 7, mtb = (qg >> 4) & 7, r16 = qg & 15;
        #pragma unroll
        for (int dt = 0; dt < 4; ++dt) {
            int k = h * 64 + dt * 16 + lg * 4;
            int ks = k >> 5, kgrp = (k >> 3) & 3, koff = k & 7;
            size_t off = ((((size_t)(bl * 2 + hf) * 24 + ks) * 512)
                          + mtb * 64 + kgrp * 16 + r16) * 8 + koff;
            union { _Float16 s[4]; uint2 u; } H;
            #pragma unroll
            for (int j = 0; j < 4; ++j)
                H.s[j] = (_Float16)(oacc[qt][dt][j] * inv);
            *(uint2*)(ao + off) = H.u;
        }
    }
}

// ---------------------------------------------------------------------------
// Proj GEMM, fp16 1-term, staged both sides + global_load_lds. grid (cb*2, 6)
// ---------------------------------------------------------------------------
__global__ __launch_bounds__(256) void proj_gemm(
    const _Float16* __restrict__ wst, const _Float16* __restrict__ ao,
    const float* __restrict__ bvec, float* __restrict__ outp,
    int b0)
{
    __shared__ __align__(16) _Float16 SW[4096], SX[4096];

    const int tid  = threadIdx.x;
    const int lane = tid & 63;
    const int wv   = tid >> 6;
    const int wr   = wv >> 1;
    const int wc   = wv & 1;
    const int bx = blockIdx.x, by = blockIdx.y;
    const int bl = bx >> 1, half = bx & 1;
    const int b  = b0 + bl;

    const size_t wq0 = (size_t)by * 24 * 4096;
    const size_t xq0 = ((size_t)bl * 2 + half) * 24 * 4096;

    f32x4 acc[4][4];
    #pragma unroll
    for (int i = 0; i < 4; ++i)
        #pragma unroll
        for (int j = 0; j < 4; ++j)
            acc[i][j] = (f32x4){0.f, 0.f, 0.f, 0.f};

    const int d0 = wv * 512;

    for (int ks = 0; ks < 24; ++ks) {
        const size_t wq = wq0 + (size_t)ks * 4096 + d0;
        const size_t xq = xq0 + (size_t)ks * 4096 + d0;
        #pragma unroll
        for (int s = 0; s < 2; ++s) {
            GLDS16(wst + wq + s * 2048 + lane * 8, &SW[d0 + s * 2048]);
            GLDS16(ao  + xq + s * 2048 + lane * 8, &SX[d0 + s * 2048]);
        }
        __syncthreads();

        half8 ah[4];
        #pragma unroll
        for (int mt = 0; mt < 4; ++mt)
            ah[mt] = *(const half8*)&SW[((wr * 4 + mt) * 64 + lane) * 8];
        #pragma unroll
        for (int nt = 0; nt < 4; ++nt) {
            half8 bh = *(const half8*)&SX[((wc * 4 + nt) * 64 + lane) * 8];
            #pragma unroll
            for (int mt = 0; mt < 4; ++mt)
                acc[mt][nt] = __builtin_amdgcn_mfma_f32_16x16x32_f16(ah[mt], bh, acc[mt][nt], 0, 0, 0);
        }
        __syncthreads();
    }

    const int ocb = by * 128 + wr * 64 + (lane >> 4) * 4;
    const int nb  = half * 128 + wc * 64 + (lane & 15);

    #pragma unroll
    for (int mt = 0; mt < 4; ++mt) {
        int oc = ocb + mt * 16;
        float4 bv = *(const float4*)(bvec + oc);
        float* obase = outp + (size_t)b * DIM_ * N_ + (size_t)oc * N_;
        #pragma unroll
        for (int nt = 0; nt < 4; ++nt) {
            int n = nb + nt * 16;
            obase[0 * N_ + n] = acc[mt][nt][0] + bv.x;
            obase[1 * N_ + n] = acc[mt][nt][1] + bv.y;
            obase[2 * N_ + n] = acc[mt][nt][2] + bv.z;
            obase[3 * N_ + n] = acc[mt][nt][3] + bv.w;
        }
    }
}

// ---------------------------------------------------------------------------
extern "C" void kernel_launch(void* const* d_in, const int* in_sizes, int n_in,
                              void* d_out, int out_size, void* d_ws, size_t ws_size,
                              hipStream_t stream)
{
    const float* x           = (const float*)d_in[0];
    const float* face_priors = (const float*)d_in[1];
    const float* qkv_w       = (const float*)d_in[2];
    const float* qkv_b       = (const float*)d_in[3];
    const float* rel_table   = (const float*)d_in[4];
    const float* face_prior  = (const float*)d_in[5];
    const float* proj_w      = (const float*)d_in[6];
    const float* proj_b      = (const float*)d_in[7];
    float* out = (float*)d_out;

    // persistent: bias 3.15MB | x staged 100.7MB | qkv_w staged 7.08MB | pw16 1.18MB
    float* ws   = (float*)d_ws;
    float* bias = ws;
    u16* xah = (u16*)(bias + 786432);
    u16* xal = xah + (size_t)B_ * N_ * DIM_;
    u16* qwh = xal + (size_t)B_ * N_ * DIM_;
    u16* qwl = qwh + (size_t)3 * DIM_ * DIM_;
    _Float16* pw16 = (_Float16*)(qwl + (size_t)3 * DIM_ * DIM_);
    u16* cbase = (u16*)(pw16 + (size_t)DIM_ * DIM_);

    // per-batch chunk: qh/ql/kh/kl/vv (bf16) + ao (fp16) = 6 * 393216 B
    int CB = 1;
    const int cands[] = {128, 64, 32, 16, 8, 4, 2, 1};
    for (int ci = 0; ci < 8; ++ci) {
        if (112066560ull + (size_t)cands[ci] * 2359296ull <= ws_size) { CB = cands[ci]; break; }
    }
    const size_t SL = (size_t)CB * NH_ * N_ * HD_;
    u16* qhb = cbase;
    u16* qlb = qhb + SL;
    u16* khb = qlb + SL;
    u16* klb = khb + SL;
    u16* vvb = klb + SL;
    _Float16* aob = (_Float16*)(vvb + SL);

    hipFuncSetAttribute((const void*)attn_mfma,
                        hipFuncAttributeMaxDynamicSharedMemorySize, 53248);

    bias_kernel<<<(NH_ * N_ * N_) / 256, 256, 0, stream>>>(face_prior, rel_table, bias);
    split_w_staged<<<(18 * 24 * 512 + 255) / 256, 256, 0, stream>>>(qkv_w, qwh, qwl, 18 * 24 * 512);
    conv_w_f16_staged<<<(6 * 24 * 512 + 255) / 256, 256, 0, stream>>>(proj_w, pw16, 6 * 24 * 512);
    split_transpose_x<<<dim3(12, 4, B_), 256, 0, stream>>>(x, xah, xal);

    for (int b0 = 0; b0 < B_; b0 += CB) {
        qkv_gemm<<<dim3(CB * 2, 18), 256, 0, stream>>>(
            qwh, qwl, xah, xal, qkv_b, qhb, qlb, khb, klb, vvb, b0, CB);

        attn_mfma<<<CB * NH_, 256, 53248, stream>>>(
            qhb, qlb, khb, klb, vvb, bias, face_priors, aob, b0, CB);

        proj_gemm<<<dim3(CB * 2, 6), 256, 0, stream>>>(
            pw16, aob, proj_b, out, b0);
    }
}

// Round 9
// 535.786 us; speedup vs baseline: 1.8025x; 1.5443x over previous
//
#include <hip/hip_runtime.h>

#define B_   128
#define DIM_ 768
#define NH_  12
#define HD_  64
#define N_   256

using half8 = __attribute__((ext_vector_type(8))) _Float16;
using f32x4 = __attribute__((ext_vector_type(4))) float;
typedef unsigned short u16;
typedef unsigned int   u32;

// Staged (fragment-major) layout: per (tile, kstep) a 128row x 32k block is
// 512 chunks of 8 elems; chunk c = mtblock*64 + kgrp*16 + row16, where
// row = mtblock*16 + row16, k = kstep*32 + kgrp*8 + koff.
// Staging chunk c = tid + s*256 -> global src AND LDS dst lane-linear
// (global_load_lds form); frag read chunk = mtb*64 + lane -> conflict-free.

#define GLDS16(srcp, dstp) \
    __builtin_amdgcn_global_load_lds( \
        (const __attribute__((address_space(1))) void*)(srcp), \
        (__attribute__((address_space(3))) void*)(dstp), 16, 0, 0)

// ---------------------------------------------------------------------------
// bias = face_prior[h,n,m] + rel_table[relidx(n,m), h]   -> [NH, N, N]
// ---------------------------------------------------------------------------
__global__ __launch_bounds__(256) void bias_kernel(
    const float* __restrict__ face_prior, const float* __restrict__ rel_table,
    float* __restrict__ bias)
{
    int idx = blockIdx.x * 256 + threadIdx.x;
    int m = idx & 255;
    int n = (idx >> 8) & 255;
    int h = idx >> 16;
    int rn = n >> 4, cn = n & 15;
    int rm = m >> 4, cm = m & 15;
    int ridx = (rn - rm + 15) * 31 + (cn - cm + 15);
    bias[idx] = face_prior[idx] + rel_table[ridx * NH_ + h];
}

// ---------------------------------------------------------------------------
// weights fp32 [T*128][768] -> fp16 staged [T][24][512][8]
// (used for qkv_w T=18 and proj_w T=6)
// ---------------------------------------------------------------------------
__global__ __launch_bounds__(256) void conv_w_f16_staged(
    const float* __restrict__ in, _Float16* __restrict__ o16, int nchunk)
{
    int gid = blockIdx.x * 256 + threadIdx.x;
    if (gid >= nchunk) return;
    int t   = gid / 12288;          // 24*512
    int rem = gid % 12288;
    int ks  = rem >> 9;
    int c   = rem & 511;
    int mtb = c >> 6, kgrp = (c >> 4) & 3, r16 = c & 15;
    int srow = t * 128 + mtb * 16 + r16;
    int sk   = ks * 32 + kgrp * 8;
    float4 a = *(const float4*)(in + (size_t)srow * DIM_ + sk);
    float4 b = *(const float4*)(in + (size_t)srow * DIM_ + sk + 4);
    float v[8] = {a.x, a.y, a.z, a.w, b.x, b.y, b.z, b.w};
    union { _Float16 s[8]; uint4 q; } H;
    #pragma unroll
    for (int j = 0; j < 8; ++j) H.s[j] = (_Float16)v[j];
    *(uint4*)(o16 + (size_t)gid * 8) = H.q;
}

// ---------------------------------------------------------------------------
// x [B,768(k),256(n)] fp32 -> fp16 staged [B][2][24][512][8]
// ---------------------------------------------------------------------------
__global__ __launch_bounds__(256) void conv_transpose_x_f16(
    const float* __restrict__ x, _Float16* __restrict__ xa)
{
    __shared__ float T[64][65];
    const int b = blockIdx.z, k0 = blockIdx.x * 64, n0 = blockIdx.y * 64;
    const int t = threadIdx.x;
    const float* xb = x + (size_t)b * DIM_ * N_;
    {
        int nn = t & 63, kg = t >> 6;
        #pragma unroll
        for (int r = 0; r < 16; ++r) {
            int kk = r * 4 + kg;
            T[kk][nn] = xb[(size_t)(k0 + kk) * N_ + n0 + nn];
        }
    }
    __syncthreads();
    {
        int kk2 = (t & 31) * 2, ng = t >> 5;
        #pragma unroll
        for (int r = 0; r < 8; ++r) {
            int nn = r * 8 + ng;
            union { _Float16 s[2]; u32 u; } P;
            P.s[0] = (_Float16)T[kk2][nn];
            P.s[1] = (_Float16)T[kk2 + 1][nn];
            int n = n0 + nn, k = k0 + kk2;
            int half = n >> 7, mtb = (n >> 4) & 7, r16 = n & 15;
            int ks = k >> 5, kgrp = (k >> 3) & 3, koff = k & 7;
            size_t o = ((((size_t)b * 2 + half) * 24 + ks) * 512
                        + mtb * 64 + kgrp * 16 + r16) * 8 + koff;
            *(u32*)(xa + o) = P.u;
        }
    }
}

// ---------------------------------------------------------------------------
// QKV GEMM: fp16 1-term MFMA, staged layout + global_load_lds (m97 structure).
// Emits q16/k16/v16 fp16 slabs [cb,NH,N,HD]. grid (cb*2, 18)
// ---------------------------------------------------------------------------
__global__ __launch_bounds__(256) void qkv_gemm(
    const _Float16* __restrict__ w16, const _Float16* __restrict__ x16,
    const float* __restrict__ bvec,
    _Float16* __restrict__ q16, _Float16* __restrict__ k16,
    _Float16* __restrict__ v16,
    int b0, int cb)
{
    __shared__ __align__(16) _Float16 SW[4096], SX[4096];   // 16 KB

    const int tid  = threadIdx.x;
    const int lane = tid & 63;
    const int wv   = tid >> 6;
    const int wr   = wv >> 1;
    const int wc   = wv & 1;
    const int bx = blockIdx.x, by = blockIdx.y;
    const int bl = bx >> 1, half = bx & 1;
    const int b  = b0 + bl;

    const size_t wq0 = (size_t)by * 24 * 4096;
    const size_t xq0 = ((size_t)b * 2 + half) * 24 * 4096;

    f32x4 acc[4][4];
    #pragma unroll
    for (int i = 0; i < 4; ++i)
        #pragma unroll
        for (int j = 0; j < 4; ++j)
            acc[i][j] = (f32x4){0.f, 0.f, 0.f, 0.f};

    const int d0 = wv * 512;   // wave-uniform LDS base (elems)

    for (int ks = 0; ks < 24; ++ks) {
        const size_t wq = wq0 + (size_t)ks * 4096 + d0;
        const size_t xq = xq0 + (size_t)ks * 4096 + d0;
        #pragma unroll
        for (int s = 0; s < 2; ++s) {
            GLDS16(w16 + wq + s * 2048 + lane * 8, &SW[d0 + s * 2048]);
            GLDS16(x16 + xq + s * 2048 + lane * 8, &SX[d0 + s * 2048]);
        }
        __syncthreads();

        half8 ah[4];
        #pragma unroll
        for (int mt = 0; mt < 4; ++mt)
            ah[mt] = *(const half8*)&SW[((wr * 4 + mt) * 64 + lane) * 8];
        #pragma unroll
        for (int nt = 0; nt < 4; ++nt) {
            half8 bh = *(const half8*)&SX[((wc * 4 + nt) * 64 + lane) * 8];
            #pragma unroll
            for (int mt = 0; mt < 4; ++mt)
                acc[mt][nt] = __builtin_amdgcn_mfma_f32_16x16x32_f16(ah[mt], bh, acc[mt][nt], 0, 0, 0);
        }
        __syncthreads();
    }

    // C/D layout: col = lane&15 (n), row = (lane>>4)*4 + reg (oc)
    const int ocb = by * 128 + wr * 64 + (lane >> 4) * 4;
    const int nb  = half * 128 + wc * 64 + (lane & 15);

    #pragma unroll
    for (int mt = 0; mt < 4; ++mt) {
        int oc = ocb + mt * 16;
        float4 bv = *(const float4*)(bvec + oc);
        int which = oc / DIM_;            // uniform per block
        int r = oc - which * DIM_;
        int hh = r >> 6, d = r & 63;
        _Float16* slab = (which == 0) ? q16 : (which == 1) ? k16 : v16;
        size_t rowbase = ((size_t)bl * NH_ + hh) * (N_ * HD_) + d;
        #pragma unroll
        for (int nt = 0; nt < 4; ++nt) {
            int n = nb + nt * 16;
            union { _Float16 s[4]; uint2 u; } H;
            H.s[0] = (_Float16)(acc[mt][nt][0] + bv.x);
            H.s[1] = (_Float16)(acc[mt][nt][1] + bv.y);
            H.s[2] = (_Float16)(acc[mt][nt][2] + bv.z);
            H.s[3] = (_Float16)(acc[mt][nt][3] + bv.w);
            *(uint2*)(slab + rowbase + (size_t)n * HD_) = H.u;
        }
    }
}

// ---------------------------------------------------------------------------
// MFMA attention, fp16, flash-chunked (2 x 128 kk, online softmax), 4 waves.
// LDS 36KB. S^T = mfma_f16(K, Q); P fp16; PV fp16. Emits ao fp16 staged.
// ---------------------------------------------------------------------------
__global__ __launch_bounds__(256, 3) void attn_mfma(
    const _Float16* __restrict__ q16, const _Float16* __restrict__ k16,
    const _Float16* __restrict__ v16,
    const float* __restrict__ bias, const float* __restrict__ fpri,
    _Float16* __restrict__ ao,
    int b0, int cb)
{
    extern __shared__ _Float16 ldsh[];
    _Float16* KL  = ldsh;            // [128][64], idx = r*64 + (kc ^ ((r&7)<<3))
    _Float16* VtL = ldsh + 8192;     // [64][128], idx = d*128 + (kk ^ ((d&7)<<3))
    const int tid  = threadIdx.x;
    const int lane = tid & 63;
    const int wv   = tid >> 6;                  // 0..3
    _Float16* PL = ldsh + 16384 + wv * 512;     // [16][32] per wave

    const int bh = blockIdx.x;
    const int bl = bh / NH_, h = bh % NH_;
    const int b  = b0 + bl;
    const size_t base = ((size_t)bl * NH_ + h) * (size_t)(N_ * HD_);

    const int l15 = lane & 15;
    const int lg  = lane >> 4;
    const int e   = (l15 & 3) << 1;            // PL swizzle

    float mrun[4], lrun[4];
    f32x4 oacc[4][4];
    #pragma unroll
    for (int qt = 0; qt < 4; ++qt) {
        mrun[qt] = -1e30f; lrun[qt] = 0.f;
        #pragma unroll
        for (int dt = 0; dt < 4; ++dt) oacc[qt][dt] = (f32x4){0.f, 0.f, 0.f, 0.f};
    }

    for (int ch = 0; ch < 2; ++ch) {
        __syncthreads();
        #pragma unroll
        for (int s = 0; s < 4; ++s) {
            int idx = tid + s * 256;                // 0..1023
            int r = idx >> 3, kc = (idx & 7) * 8;
            int di = r * 64 + (kc ^ ((r & 7) << 3));
            *(half8*)&KL[di] = *(const half8*)(k16 + base + (size_t)(ch * 128 + r) * 64 + kc);
        }
        #pragma unroll
        for (int s = 0; s < 4; ++s) {
            int idx = tid + s * 256;
            int d = idx & 63, kkc = (idx >> 6) * 8;
            union { _Float16 s[8]; half8 v; } t;
            #pragma unroll
            for (int j = 0; j < 8; ++j)
                t.s[j] = v16[base + (size_t)(ch * 128 + kkc + j) * 64 + d];
            *(half8*)&VtL[d * 128 + (kkc ^ ((d & 7) << 3))] = t.v;
        }
        __syncthreads();

        for (int qt = 0; qt < 4; ++qt) {
            const int qg = wv * 64 + qt * 16 + l15;
            const size_t qrow = base + (size_t)qg * 64;
            half8 bq[2];
            #pragma unroll
            for (int c = 0; c < 2; ++c)
                bq[c] = *(const half8*)(q16 + qrow + lg * 8 + c * 32);

            f32x4 sacc[8];
            const float* brow = bias + ((size_t)h * N_ + qg) * N_ + ch * 128;
            const float* frow = fpri + ((size_t)b * N_ + qg) * N_ + ch * 128;
            #pragma unroll
            for (int kt = 0; kt < 8; ++kt) {
                f32x4 sa = (f32x4){0.f, 0.f, 0.f, 0.f};
                int kr = kt * 16 + l15;
                #pragma unroll
                for (int c = 0; c < 2; ++c) {
                    int kc = lg * 8 + c * 32;
                    half8 ah = *(const half8*)&KL[kr * 64 + (kc ^ ((kr & 7) << 3))];
                    sa = __builtin_amdgcn_mfma_f32_16x16x32_f16(ah, bq[c], sa, 0, 0, 0);
                }
                float4 bs = *(const float4*)(brow + kt * 16 + lg * 4);
                float4 fs = *(const float4*)(frow + kt * 16 + lg * 4);
                sacc[kt][0] = (sa[0] * 0.125f + bs.x) * fs.x;
                sacc[kt][1] = (sa[1] * 0.125f + bs.y) * fs.y;
                sacc[kt][2] = (sa[2] * 0.125f + bs.z) * fs.z;
                sacc[kt][3] = (sa[3] * 0.125f + bs.w) * fs.w;
            }

            float cmax = -1e30f;
            #pragma unroll
            for (int kt = 0; kt < 8; ++kt)
                cmax = fmaxf(cmax, fmaxf(fmaxf(sacc[kt][0], sacc[kt][1]),
                                         fmaxf(sacc[kt][2], sacc[kt][3])));
            cmax = fmaxf(cmax, __shfl_xor(cmax, 16));
            cmax = fmaxf(cmax, __shfl_xor(cmax, 32));
            float mnew = fmaxf(mrun[qt], cmax);
            float corr = __expf(mrun[qt] - mnew);
            mrun[qt] = mnew;
            float csum = 0.f;
            #pragma unroll
            for (int kt = 0; kt < 8; ++kt) {
                #pragma unroll
                for (int j = 0; j < 4; ++j) {
                    float p = __expf(sacc[kt][j] - mnew);
                    sacc[kt][j] = p;
                    csum += p;
                }
            }
            csum += __shfl_xor(csum, 16);
            csum += __shfl_xor(csum, 32);
            lrun[qt] = lrun[qt] * corr + csum;
            #pragma unroll
            for (int dt = 0; dt < 4; ++dt) {
                oacc[qt][dt][0] *= corr; oacc[qt][dt][1] *= corr;
                oacc[qt][dt][2] *= corr; oacc[qt][dt][3] *= corr;
            }

            #pragma unroll
            for (int c2 = 0; c2 < 4; ++c2) {
                #pragma unroll
                for (int t = 0; t < 2; ++t) {
                    int kt = c2 * 2 + t;
                    union { _Float16 s[4]; uint2 u; } pw;
                    pw.s[0] = (_Float16)sacc[kt][0];
                    pw.s[1] = (_Float16)sacc[kt][1];
                    pw.s[2] = (_Float16)sacc[kt][2];
                    pw.s[3] = (_Float16)sacc[kt][3];
                    int u = (4 * t + lg) ^ e;
                    *(uint2*)&PL[l15 * 32 + u * 4] = pw.u;
                }
                half8 bp = *(const half8*)&PL[l15 * 32 + ((2 * lg) ^ e) * 4];
                int kc2 = lg * 8 + c2 * 32;
                #pragma unroll
                for (int dt = 0; dt < 4; ++dt) {
                    int dr = dt * 16 + l15;
                    half8 av = *(const half8*)&VtL[dr * 128 + (kc2 ^ ((dr & 7) << 3))];
                    oacc[qt][dt] = __builtin_amdgcn_mfma_f32_16x16x32_f16(av, bp, oacc[qt][dt], 0, 0, 0);
                }
            }
        }
    }

    // epilogue: scale by 1/l, emit fp16 in staged layout [bl][2][24][512][8]
    #pragma unroll
    for (int qt = 0; qt < 4; ++qt) {
        const int qg = wv * 64 + qt * 16 + l15;
        float inv = 1.f / lrun[qt];
        const int hf  = qg >> 7, mtb = (qg >> 4) & 7, r16 = qg & 15;
        #pragma unroll
        for (int dt = 0; dt < 4; ++dt) {
            int k = h * 64 + dt * 16 + lg * 4;
            int ks = k >> 5, kgrp = (k >> 3) & 3, koff = k & 7;
            size_t off = ((((size_t)(bl * 2 + hf) * 24 + ks) * 512)
                          + mtb * 64 + kgrp * 16 + r16) * 8 + koff;
            union { _Float16 s[4]; uint2 u; } H;
            #pragma unroll
            for (int j = 0; j < 4; ++j)
                H.s[j] = (_Float16)(oacc[qt][dt][j] * inv);
            *(uint2*)(ao + off) = H.u;
        }
    }
}

// ---------------------------------------------------------------------------
// Proj GEMM, fp16 1-term, staged both sides + global_load_lds. grid (cb*2, 6)
// ---------------------------------------------------------------------------
__global__ __launch_bounds__(256) void proj_gemm(
    const _Float16* __restrict__ wst, const _Float16* __restrict__ ao,
    const float* __restrict__ bvec, float* __restrict__ outp,
    int b0)
{
    __shared__ __align__(16) _Float16 SW[4096], SX[4096];

    const int tid  = threadIdx.x;
    const int lane = tid & 63;
    const int wv   = tid >> 6;
    const int wr   = wv >> 1;
    const int wc   = wv & 1;
    const int bx = blockIdx.x, by = blockIdx.y;
    const int bl = bx >> 1, half = bx & 1;
    const int b  = b0 + bl;

    const size_t wq0 = (size_t)by * 24 * 4096;
    const size_t xq0 = ((size_t)bl * 2 + half) * 24 * 4096;

    f32x4 acc[4][4];
    #pragma unroll
    for (int i = 0; i < 4; ++i)
        #pragma unroll
        for (int j = 0; j < 4; ++j)
            acc[i][j] = (f32x4){0.f, 0.f, 0.f, 0.f};

    const int d0 = wv * 512;

    for (int ks = 0; ks < 24; ++ks) {
        const size_t wq = wq0 + (size_t)ks * 4096 + d0;
        const size_t xq = xq0 + (size_t)ks * 4096 + d0;
        #pragma unroll
        for (int s = 0; s < 2; ++s) {
            GLDS16(wst + wq + s * 2048 + lane * 8, &SW[d0 + s * 2048]);
            GLDS16(ao  + xq + s * 2048 + lane * 8, &SX[d0 + s * 2048]);
        }
        __syncthreads();

        half8 ah[4];
        #pragma unroll
        for (int mt = 0; mt < 4; ++mt)
            ah[mt] = *(const half8*)&SW[((wr * 4 + mt) * 64 + lane) * 8];
        #pragma unroll
        for (int nt = 0; nt < 4; ++nt) {
            half8 bh = *(const half8*)&SX[((wc * 4 + nt) * 64 + lane) * 8];
            #pragma unroll
            for (int mt = 0; mt < 4; ++mt)
                acc[mt][nt] = __builtin_amdgcn_mfma_f32_16x16x32_f16(ah[mt], bh, acc[mt][nt], 0, 0, 0);
        }
        __syncthreads();
    }

    const int ocb = by * 128 + wr * 64 + (lane >> 4) * 4;
    const int nb  = half * 128 + wc * 64 + (lane & 15);

    #pragma unroll
    for (int mt = 0; mt < 4; ++mt) {
        int oc = ocb + mt * 16;
        float4 bv = *(const float4*)(bvec + oc);
        float* obase = outp + (size_t)b * DIM_ * N_ + (size_t)oc * N_;
        #pragma unroll
        for (int nt = 0; nt < 4; ++nt) {
            int n = nb + nt * 16;
            obase[0 * N_ + n] = acc[mt][nt][0] + bv.x;
            obase[1 * N_ + n] = acc[mt][nt][1] + bv.y;
            obase[2 * N_ + n] = acc[mt][nt][2] + bv.z;
            obase[3 * N_ + n] = acc[mt][nt][3] + bv.w;
        }
    }
}

// ---------------------------------------------------------------------------
extern "C" void kernel_launch(void* const* d_in, const int* in_sizes, int n_in,
                              void* d_out, int out_size, void* d_ws, size_t ws_size,
                              hipStream_t stream)
{
    const float* x           = (const float*)d_in[0];
    const float* face_priors = (const float*)d_in[1];
    const float* qkv_w       = (const float*)d_in[2];
    const float* qkv_b       = (const float*)d_in[3];
    const float* rel_table   = (const float*)d_in[4];
    const float* face_prior  = (const float*)d_in[5];
    const float* proj_w      = (const float*)d_in[6];
    const float* proj_b      = (const float*)d_in[7];
    float* out = (float*)d_out;

    // persistent: bias 3.15MB | xa16 50.3MB | qw16 3.54MB | pw16 1.18MB = 58.2MB
    float* ws   = (float*)d_ws;
    float* bias = ws;
    _Float16* xa16 = (_Float16*)(bias + 786432);
    _Float16* qw16 = xa16 + (size_t)B_ * N_ * DIM_;
    _Float16* pw16 = qw16 + (size_t)3 * DIM_ * DIM_;
    _Float16* cbase = pw16 + (size_t)DIM_ * DIM_;

    // per-batch chunk: q16/k16/v16/ao = 4 * cb * 393216 B
    int CB = 1;
    const int cands[] = {128, 64, 32, 16, 8, 4, 2, 1};
    for (int ci = 0; ci < 8; ++ci) {
        if (58195968ull + (size_t)cands[ci] * 1572864ull <= ws_size) { CB = cands[ci]; break; }
    }
    const size_t SL = (size_t)CB * NH_ * N_ * HD_;
    _Float16* q16b = cbase;
    _Float16* k16b = q16b + SL;
    _Float16* v16b = k16b + SL;
    _Float16* aob  = v16b + SL;

    hipFuncSetAttribute((const void*)attn_mfma,
                        hipFuncAttributeMaxDynamicSharedMemorySize, 36864);

    bias_kernel<<<(NH_ * N_ * N_) / 256, 256, 0, stream>>>(face_prior, rel_table, bias);
    conv_w_f16_staged<<<(18 * 12288 + 255) / 256, 256, 0, stream>>>(qkv_w, qw16, 18 * 12288);
    conv_w_f16_staged<<<(6 * 12288 + 255) / 256, 256, 0, stream>>>(proj_w, pw16, 6 * 12288);
    conv_transpose_x_f16<<<dim3(12, 4, B_), 256, 0, stream>>>(x, xa16);

    for (int b0 = 0; b0 < B_; b0 += CB) {
        qkv_gemm<<<dim3(CB * 2, 18), 256, 0, stream>>>(
            qw16, xa16, qkv_b, q16b, k16b, v16b, b0, CB);

        attn_mfma<<<CB * NH_, 256, 36864, stream>>>(
            q16b, k16b, v16b, bias, face_priors, aob, b0, CB);

        proj_gemm<<<dim3(CB * 2, 6), 256, 0, stream>>>(
            pw16, aob, proj_b, out, b0);
    }
}

// Round 10
// 517.712 us; speedup vs baseline: 1.8654x; 1.0349x over previous
//
#include <hip/hip_runtime.h>

#define B_   128
#define DIM_ 768
#define NH_  12
#define HD_  64
#define N_   256

using half8 = __attribute__((ext_vector_type(8))) _Float16;
using half4 = __attribute__((ext_vector_type(4))) _Float16;
using f32x4 = __attribute__((ext_vector_type(4))) float;
typedef unsigned short u16;
typedef unsigned int   u32;

// Staged (fragment-major) layout: per (tile, kstep) a 128row x 32k block is
// 512 chunks of 8 elems; chunk c = mtblock*64 + kgrp*16 + row16, where
// row = mtblock*16 + row16, k = kstep*32 + kgrp*8 + koff.
// Staging chunk c = tid + s*256 -> global src AND LDS dst lane-linear
// (global_load_lds form); frag read chunk = mtb*64 + lane -> conflict-free.

#define GLDS16(srcp, dstp) \
    __builtin_amdgcn_global_load_lds( \
        (const __attribute__((address_space(1))) void*)(srcp), \
        (__attribute__((address_space(3))) void*)(dstp), 16, 0, 0)

// ---------------------------------------------------------------------------
// bias16 = fp16(face_prior[h,n,m] + rel_table[relidx(n,m), h]) -> [NH, N, N]
// 2 elems per thread (u32 store)
// ---------------------------------------------------------------------------
__global__ __launch_bounds__(256) void bias16_kernel(
    const float* __restrict__ face_prior, const float* __restrict__ rel_table,
    _Float16* __restrict__ b16)
{
    int gid = blockIdx.x * 256 + threadIdx.x;    // over NH*N*N/2
    int idx = gid * 2;
    union { _Float16 s[2]; u32 u; } P;
    #pragma unroll
    for (int j = 0; j < 2; ++j) {
        int id = idx + j;
        int m = id & 255;
        int n = (id >> 8) & 255;
        int h = id >> 16;
        int rn = n >> 4, cn = n & 15;
        int rm = m >> 4, cm = m & 15;
        int ridx = (rn - rm + 15) * 31 + (cn - cm + 15);
        P.s[j] = (_Float16)(face_prior[id] + rel_table[ridx * NH_ + h]);
    }
    *(u32*)(b16 + idx) = P.u;
}

// ---------------------------------------------------------------------------
// generic fp32 -> fp16 linear conversion (8 elems/thread); for face_priors
// ---------------------------------------------------------------------------
__global__ __launch_bounds__(256) void conv_f32_f16(
    const float* __restrict__ in, _Float16* __restrict__ o16, int n8)
{
    int i = blockIdx.x * 256 + threadIdx.x;
    if (i >= n8) return;
    float4 a = *(const float4*)(in + (size_t)i * 8);
    float4 b = *(const float4*)(in + (size_t)i * 8 + 4);
    float v[8] = {a.x, a.y, a.z, a.w, b.x, b.y, b.z, b.w};
    union { _Float16 s[8]; uint4 q; } H;
    #pragma unroll
    for (int j = 0; j < 8; ++j) H.s[j] = (_Float16)v[j];
    *(uint4*)(o16 + (size_t)i * 8) = H.q;
}

// ---------------------------------------------------------------------------
// weights fp32 [T*128][768] -> fp16 staged [T][24][512][8]
// ---------------------------------------------------------------------------
__global__ __launch_bounds__(256) void conv_w_f16_staged(
    const float* __restrict__ in, _Float16* __restrict__ o16, int nchunk)
{
    int gid = blockIdx.x * 256 + threadIdx.x;
    if (gid >= nchunk) return;
    int t   = gid / 12288;          // 24*512
    int rem = gid % 12288;
    int ks  = rem >> 9;
    int c   = rem & 511;
    int mtb = c >> 6, kgrp = (c >> 4) & 3, r16 = c & 15;
    int srow = t * 128 + mtb * 16 + r16;
    int sk   = ks * 32 + kgrp * 8;
    float4 a = *(const float4*)(in + (size_t)srow * DIM_ + sk);
    float4 b = *(const float4*)(in + (size_t)srow * DIM_ + sk + 4);
    float v[8] = {a.x, a.y, a.z, a.w, b.x, b.y, b.z, b.w};
    union { _Float16 s[8]; uint4 q; } H;
    #pragma unroll
    for (int j = 0; j < 8; ++j) H.s[j] = (_Float16)v[j];
    *(uint4*)(o16 + (size_t)gid * 8) = H.q;
}

// ---------------------------------------------------------------------------
// x [B,768(k),256(n)] fp32 -> fp16 staged [B][2][24][512][8]
// ---------------------------------------------------------------------------
__global__ __launch_bounds__(256) void conv_transpose_x_f16(
    const float* __restrict__ x, _Float16* __restrict__ xa)
{
    __shared__ float T[64][65];
    const int b = blockIdx.z, k0 = blockIdx.x * 64, n0 = blockIdx.y * 64;
    const int t = threadIdx.x;
    const float* xb = x + (size_t)b * DIM_ * N_;
    {
        int nn = t & 63, kg = t >> 6;
        #pragma unroll
        for (int r = 0; r < 16; ++r) {
            int kk = r * 4 + kg;
            T[kk][nn] = xb[(size_t)(k0 + kk) * N_ + n0 + nn];
        }
    }
    __syncthreads();
    {
        int kk2 = (t & 31) * 2, ng = t >> 5;
        #pragma unroll
        for (int r = 0; r < 8; ++r) {
            int nn = r * 8 + ng;
            union { _Float16 s[2]; u32 u; } P;
            P.s[0] = (_Float16)T[kk2][nn];
            P.s[1] = (_Float16)T[kk2 + 1][nn];
            int n = n0 + nn, k = k0 + kk2;
            int half = n >> 7, mtb = (n >> 4) & 7, r16 = n & 15;
            int ks = k >> 5, kgrp = (k >> 3) & 3, koff = k & 7;
            size_t o = ((((size_t)b * 2 + half) * 24 + ks) * 512
                        + mtb * 64 + kgrp * 16 + r16) * 8 + koff;
            *(u32*)(xa + o) = P.u;
        }
    }
}

// ---------------------------------------------------------------------------
// QKV GEMM: fp16 1-term MFMA, staged layout + global_load_lds (m97 structure).
// Emits q16/k16/v16 fp16 slabs [cb,NH,N,HD]. grid (cb*2, 18)
// ---------------------------------------------------------------------------
__global__ __launch_bounds__(256) void qkv_gemm(
    const _Float16* __restrict__ w16, const _Float16* __restrict__ x16,
    const float* __restrict__ bvec,
    _Float16* __restrict__ q16, _Float16* __restrict__ k16,
    _Float16* __restrict__ v16,
    int b0, int cb)
{
    __shared__ __align__(16) _Float16 SW[4096], SX[4096];   // 16 KB

    const int tid  = threadIdx.x;
    const int lane = tid & 63;
    const int wv   = tid >> 6;
    const int wr   = wv >> 1;
    const int wc   = wv & 1;
    const int bx = blockIdx.x, by = blockIdx.y;
    const int bl = bx >> 1, half = bx & 1;
    const int b  = b0 + bl;

    const size_t wq0 = (size_t)by * 24 * 4096;
    const size_t xq0 = ((size_t)b * 2 + half) * 24 * 4096;

    f32x4 acc[4][4];
    #pragma unroll
    for (int i = 0; i < 4; ++i)
        #pragma unroll
        for (int j = 0; j < 4; ++j)
            acc[i][j] = (f32x4){0.f, 0.f, 0.f, 0.f};

    const int d0 = wv * 512;   // wave-uniform LDS base (elems)

    for (int ks = 0; ks < 24; ++ks) {
        const size_t wq = wq0 + (size_t)ks * 4096 + d0;
        const size_t xq = xq0 + (size_t)ks * 4096 + d0;
        #pragma unroll
        for (int s = 0; s < 2; ++s) {
            GLDS16(w16 + wq + s * 2048 + lane * 8, &SW[d0 + s * 2048]);
            GLDS16(x16 + xq + s * 2048 + lane * 8, &SX[d0 + s * 2048]);
        }
        __syncthreads();

        half8 ah[4];
        #pragma unroll
        for (int mt = 0; mt < 4; ++mt)
            ah[mt] = *(const half8*)&SW[((wr * 4 + mt) * 64 + lane) * 8];
        #pragma unroll
        for (int nt = 0; nt < 4; ++nt) {
            half8 bh = *(const half8*)&SX[((wc * 4 + nt) * 64 + lane) * 8];
            #pragma unroll
            for (int mt = 0; mt < 4; ++mt)
                acc[mt][nt] = __builtin_amdgcn_mfma_f32_16x16x32_f16(ah[mt], bh, acc[mt][nt], 0, 0, 0);
        }
        __syncthreads();
    }

    // C/D layout: col = lane&15 (n), row = (lane>>4)*4 + reg (oc)
    const int ocb = by * 128 + wr * 64 + (lane >> 4) * 4;
    const int nb  = half * 128 + wc * 64 + (lane & 15);

    #pragma unroll
    for (int mt = 0; mt < 4; ++mt) {
        int oc = ocb + mt * 16;
        float4 bv = *(const float4*)(bvec + oc);
        int which = oc / DIM_;            // uniform per block
        int r = oc - which * DIM_;
        int hh = r >> 6, d = r & 63;
        _Float16* slab = (which == 0) ? q16 : (which == 1) ? k16 : v16;
        size_t rowbase = ((size_t)bl * NH_ + hh) * (N_ * HD_) + d;
        #pragma unroll
        for (int nt = 0; nt < 4; ++nt) {
            int n = nb + nt * 16;
            union { _Float16 s[4]; uint2 u; } H;
            H.s[0] = (_Float16)(acc[mt][nt][0] + bv.x);
            H.s[1] = (_Float16)(acc[mt][nt][1] + bv.y);
            H.s[2] = (_Float16)(acc[mt][nt][2] + bv.z);
            H.s[3] = (_Float16)(acc[mt][nt][3] + bv.w);
            *(uint2*)(slab + rowbase + (size_t)n * HD_) = H.u;
        }
    }
}

// ---------------------------------------------------------------------------
// MFMA attention, fp16, flash-chunked (2 x 128 kk), 4 waves, FULLY UNROLLED
// qt loop (keeps oacc in registers — r9's runtime-qt indexing spilled to
// scratch: VGPR=84, WRITE 8x). bias/fpri read as fp16. XCD-swizzled grid.
// LDS 36KB.
// ---------------------------------------------------------------------------
__global__ __launch_bounds__(256, 3) void attn_mfma(
    const _Float16* __restrict__ q16, const _Float16* __restrict__ k16,
    const _Float16* __restrict__ v16,
    const _Float16* __restrict__ bias16, const _Float16* __restrict__ fpri16,
    _Float16* __restrict__ ao,
    int b0, int cb)
{
    extern __shared__ _Float16 ldsh[];
    _Float16* KL  = ldsh;            // [128][64], idx = r*64 + (kc ^ ((r&7)<<3))
    _Float16* VtL = ldsh + 8192;     // [64][128], idx = d*128 + (kk ^ ((d&7)<<3))
    const int tid  = threadIdx.x;
    const int lane = tid & 63;
    const int wv   = tid >> 6;                  // 0..3
    _Float16* PL = ldsh + 16384 + wv * 512;     // [16][32] per wave

    // m204 bijective XCD swizzle: co-locate same-b blocks (share fpri[b]) per XCD
    const int nwg = cb * NH_;
    const int orig = blockIdx.x;
    const int xcd = orig & 7, loc = orig >> 3;
    const int qq = nwg >> 3, rr = nwg & 7;
    const int bh = (xcd < rr ? xcd * (qq + 1) : rr * (qq + 1) + (xcd - rr) * qq) + loc;

    const int bl = bh / NH_, h = bh % NH_;
    const int b  = b0 + bl;
    const size_t base = ((size_t)bl * NH_ + h) * (size_t)(N_ * HD_);

    const int l15 = lane & 15;
    const int lg  = lane >> 4;
    const int e   = (l15 & 3) << 1;            // PL swizzle

    float mrun[4], lrun[4];
    f32x4 oacc[4][4];
    #pragma unroll
    for (int qt = 0; qt < 4; ++qt) {
        mrun[qt] = -1e30f; lrun[qt] = 0.f;
        #pragma unroll
        for (int dt = 0; dt < 4; ++dt) oacc[qt][dt] = (f32x4){0.f, 0.f, 0.f, 0.f};
    }

    for (int ch = 0; ch < 2; ++ch) {
        __syncthreads();
        #pragma unroll
        for (int s = 0; s < 4; ++s) {
            int idx = tid + s * 256;                // 0..1023
            int r = idx >> 3, kc = (idx & 7) * 8;
            int di = r * 64 + (kc ^ ((r & 7) << 3));
            *(half8*)&KL[di] = *(const half8*)(k16 + base + (size_t)(ch * 128 + r) * 64 + kc);
        }
        #pragma unroll
        for (int s = 0; s < 4; ++s) {
            int idx = tid + s * 256;
            int d = idx & 63, kkc = (idx >> 6) * 8;
            union { _Float16 s[8]; half8 v; } t;
            #pragma unroll
            for (int j = 0; j < 8; ++j)
                t.s[j] = v16[base + (size_t)(ch * 128 + kkc + j) * 64 + d];
            *(half8*)&VtL[d * 128 + (kkc ^ ((d & 7) << 3))] = t.v;
        }
        __syncthreads();

        #pragma unroll
        for (int qt = 0; qt < 4; ++qt) {
            const int qg = wv * 64 + qt * 16 + l15;
            const size_t qrow = base + (size_t)qg * 64;
            half8 bq[2];
            #pragma unroll
            for (int c = 0; c < 2; ++c)
                bq[c] = *(const half8*)(q16 + qrow + lg * 8 + c * 32);

            f32x4 sacc[8];
            const _Float16* brow = bias16 + ((size_t)h * N_ + qg) * N_ + ch * 128;
            const _Float16* frow = fpri16 + ((size_t)b * N_ + qg) * N_ + ch * 128;
            #pragma unroll
            for (int kt = 0; kt < 8; ++kt) {
                f32x4 sa = (f32x4){0.f, 0.f, 0.f, 0.f};
                int kr = kt * 16 + l15;
                #pragma unroll
                for (int c = 0; c < 2; ++c) {
                    int kc = lg * 8 + c * 32;
                    half8 ah = *(const half8*)&KL[kr * 64 + (kc ^ ((kr & 7) << 3))];
                    sa = __builtin_amdgcn_mfma_f32_16x16x32_f16(ah, bq[c], sa, 0, 0, 0);
                }
                half4 bsv = *(const half4*)(brow + kt * 16 + lg * 4);
                half4 fsv = *(const half4*)(frow + kt * 16 + lg * 4);
                sacc[kt][0] = (sa[0] * 0.125f + (float)bsv[0]) * (float)fsv[0];
                sacc[kt][1] = (sa[1] * 0.125f + (float)bsv[1]) * (float)fsv[1];
                sacc[kt][2] = (sa[2] * 0.125f + (float)bsv[2]) * (float)fsv[2];
                sacc[kt][3] = (sa[3] * 0.125f + (float)bsv[3]) * (float)fsv[3];
            }

            float cmax = -1e30f;
            #pragma unroll
            for (int kt = 0; kt < 8; ++kt)
                cmax = fmaxf(cmax, fmaxf(fmaxf(sacc[kt][0], sacc[kt][1]),
                                         fmaxf(sacc[kt][2], sacc[kt][3])));
            cmax = fmaxf(cmax, __shfl_xor(cmax, 16));
            cmax = fmaxf(cmax, __shfl_xor(cmax, 32));
            float mnew = fmaxf(mrun[qt], cmax);
            float corr = __expf(mrun[qt] - mnew);
            mrun[qt] = mnew;
            float csum = 0.f;
            #pragma unroll
            for (int kt = 0; kt < 8; ++kt) {
                #pragma unroll
                for (int j = 0; j < 4; ++j) {
                    float p = __expf(sacc[kt][j] - mnew);
                    sacc[kt][j] = p;
                    csum += p;
                }
            }
            csum += __shfl_xor(csum, 16);
            csum += __shfl_xor(csum, 32);
            lrun[qt] = lrun[qt] * corr + csum;
            #pragma unroll
            for (int dt = 0; dt < 4; ++dt) {
                oacc[qt][dt][0] *= corr; oacc[qt][dt][1] *= corr;
                oacc[qt][dt][2] *= corr; oacc[qt][dt][3] *= corr;
            }

            #pragma unroll
            for (int c2 = 0; c2 < 4; ++c2) {
                #pragma unroll
                for (int t = 0; t < 2; ++t) {
                    int kt = c2 * 2 + t;
                    union { _Float16 s[4]; uint2 u; } pw;
                    pw.s[0] = (_Float16)sacc[kt][0];
                    pw.s[1] = (_Float16)sacc[kt][1];
                    pw.s[2] = (_Float16)sacc[kt][2];
                    pw.s[3] = (_Float16)sacc[kt][3];
                    int u = (4 * t + lg) ^ e;
                    *(uint2*)&PL[l15 * 32 + u * 4] = pw.u;
                }
                half8 bp = *(const half8*)&PL[l15 * 32 + ((2 * lg) ^ e) * 4];
                int kc2 = lg * 8 + c2 * 32;
                #pragma unroll
                for (int dt = 0; dt < 4; ++dt) {
                    int dr = dt * 16 + l15;
                    half8 av = *(const half8*)&VtL[dr * 128 + (kc2 ^ ((dr & 7) << 3))];
                    oacc[qt][dt] = __builtin_amdgcn_mfma_f32_16x16x32_f16(av, bp, oacc[qt][dt], 0, 0, 0);
                }
            }
        }
    }

    // epilogue: scale by 1/l, emit fp16 in staged layout [bl][2][24][512][8]
    #pragma unroll
    for (int qt = 0; qt < 4; ++qt) {
        const int qg = wv * 64 + qt * 16 + l15;
        float inv = 1.f / lrun[qt];
        const int hf  = qg >> 7, mtb = (qg >> 4) & 7, r16 = qg & 15;
        #pragma unroll
        for (int dt = 0; dt < 4; ++dt) {
            int k = h * 64 + dt * 16 + lg * 4;
            int ks = k >> 5, kgrp = (k >> 3) & 3, koff = k & 7;
            size_t off = ((((size_t)(bl * 2 + hf) * 24 + ks) * 512)
                          + mtb * 64 + kgrp * 16 + r16) * 8 + koff;
            union { _Float16 s[4]; uint2 u; } H;
            #pragma unroll
            for (int j = 0; j < 4; ++j)
                H.s[j] = (_Float16)(oacc[qt][dt][j] * inv);
            *(uint2*)(ao + off) = H.u;
        }
    }
}

// ---------------------------------------------------------------------------
// Proj GEMM, fp16 1-term, staged both sides + global_load_lds. grid (cb*2, 6)
// ---------------------------------------------------------------------------
__global__ __launch_bounds__(256) void proj_gemm(
    const _Float16* __restrict__ wst, const _Float16* __restrict__ ao,
    const float* __restrict__ bvec, float* __restrict__ outp,
    int b0)
{
    __shared__ __align__(16) _Float16 SW[4096], SX[4096];

    const int tid  = threadIdx.x;
    const int lane = tid & 63;
    const int wv   = tid >> 6;
    const int wr   = wv >> 1;
    const int wc   = wv & 1;
    const int bx = blockIdx.x, by = blockIdx.y;
    const int bl = bx >> 1, half = bx & 1;
    const int b  = b0 + bl;

    const size_t wq0 = (size_t)by * 24 * 4096;
    const size_t xq0 = ((size_t)bl * 2 + half) * 24 * 4096;

    f32x4 acc[4][4];
    #pragma unroll
    for (int i = 0; i < 4; ++i)
        #pragma unroll
        for (int j = 0; j < 4; ++j)
            acc[i][j] = (f32x4){0.f, 0.f, 0.f, 0.f};

    const int d0 = wv * 512;

    for (int ks = 0; ks < 24; ++ks) {
        const size_t wq = wq0 + (size_t)ks * 4096 + d0;
        const size_t xq = xq0 + (size_t)ks * 4096 + d0;
        #pragma unroll
        for (int s = 0; s < 2; ++s) {
            GLDS16(wst + wq + s * 2048 + lane * 8, &SW[d0 + s * 2048]);
            GLDS16(ao  + xq + s * 2048 + lane * 8, &SX[d0 + s * 2048]);
        }
        __syncthreads();

        half8 ah[4];
        #pragma unroll
        for (int mt = 0; mt < 4; ++mt)
            ah[mt] = *(const half8*)&SW[((wr * 4 + mt) * 64 + lane) * 8];
        #pragma unroll
        for (int nt = 0; nt < 4; ++nt) {
            half8 bh = *(const half8*)&SX[((wc * 4 + nt) * 64 + lane) * 8];
            #pragma unroll
            for (int mt = 0; mt < 4; ++mt)
                acc[mt][nt] = __builtin_amdgcn_mfma_f32_16x16x32_f16(ah[mt], bh, acc[mt][nt], 0, 0, 0);
        }
        __syncthreads();
    }

    const int ocb = by * 128 + wr * 64 + (lane >> 4) * 4;
    const int nb  = half * 128 + wc * 64 + (lane & 15);

    #pragma unroll
    for (int mt = 0; mt < 4; ++mt) {
        int oc = ocb + mt * 16;
        float4 bv = *(const float4*)(bvec + oc);
        float* obase = outp + (size_t)b * DIM_ * N_ + (size_t)oc * N_;
        #pragma unroll
        for (int nt = 0; nt < 4; ++nt) {
            int n = nb + nt * 16;
            obase[0 * N_ + n] = acc[mt][nt][0] + bv.x;
            obase[1 * N_ + n] = acc[mt][nt][1] + bv.y;
            obase[2 * N_ + n] = acc[mt][nt][2] + bv.z;
            obase[3 * N_ + n] = acc[mt][nt][3] + bv.w;
        }
    }
}

// ---------------------------------------------------------------------------
extern "C" void kernel_launch(void* const* d_in, const int* in_sizes, int n_in,
                              void* d_out, int out_size, void* d_ws, size_t ws_size,
                              hipStream_t stream)
{
    const float* x           = (const float*)d_in[0];
    const float* face_priors = (const float*)d_in[1];
    const float* qkv_w       = (const float*)d_in[2];
    const float* qkv_b       = (const float*)d_in[3];
    const float* rel_table   = (const float*)d_in[4];
    const float* face_prior  = (const float*)d_in[5];
    const float* proj_w      = (const float*)d_in[6];
    const float* proj_b      = (const float*)d_in[7];
    float* out = (float*)d_out;

    // persistent (fp16): bias16 1.57MB | fpri16 16.78MB | xa16 50.3MB
    //                  | qw16 3.54MB | pw16 1.18MB  = 73.4MB
    _Float16* b16   = (_Float16*)d_ws;
    _Float16* fp16p = b16 + (size_t)NH_ * N_ * N_;
    _Float16* xa16  = fp16p + (size_t)B_ * N_ * N_;
    _Float16* qw16  = xa16 + (size_t)B_ * N_ * DIM_;
    _Float16* pw16  = qw16 + (size_t)3 * DIM_ * DIM_;
    _Float16* cbase = pw16 + (size_t)DIM_ * DIM_;

    // per-batch chunk: q16/k16/v16/ao = 4 * cb * 393216 B
    const size_t PERSIST = 2ull * (NH_ * N_ * N_ + (size_t)B_ * N_ * N_
                         + (size_t)B_ * N_ * DIM_ + 4ull * DIM_ * DIM_);
    int CB = 1;
    const int cands[] = {128, 64, 32, 16, 8, 4, 2, 1};
    for (int ci = 0; ci < 8; ++ci) {
        if (PERSIST + (size_t)cands[ci] * 1572864ull <= ws_size) { CB = cands[ci]; break; }
    }
    const size_t SL = (size_t)CB * NH_ * N_ * HD_;
    _Float16* q16b = cbase;
    _Float16* k16b = q16b + SL;
    _Float16* v16b = k16b + SL;
    _Float16* aob  = v16b + SL;

    hipFuncSetAttribute((const void*)attn_mfma,
                        hipFuncAttributeMaxDynamicSharedMemorySize, 36864);

    bias16_kernel<<<(NH_ * N_ * N_ / 2) / 256, 256, 0, stream>>>(face_prior, rel_table, b16);
    conv_f32_f16<<<((B_ * N_ * N_ / 8) + 255) / 256, 256, 0, stream>>>(face_priors, fp16p, B_ * N_ * N_ / 8);
    conv_w_f16_staged<<<(18 * 12288 + 255) / 256, 256, 0, stream>>>(qkv_w, qw16, 18 * 12288);
    conv_w_f16_staged<<<(6 * 12288 + 255) / 256, 256, 0, stream>>>(proj_w, pw16, 6 * 12288);
    conv_transpose_x_f16<<<dim3(12, 4, B_), 256, 0, stream>>>(x, xa16);

    for (int b0 = 0; b0 < B_; b0 += CB) {
        qkv_gemm<<<dim3(CB * 2, 18), 256, 0, stream>>>(
            qw16, xa16, qkv_b, q16b, k16b, v16b, b0, CB);

        attn_mfma<<<CB * NH_, 256, 36864, stream>>>(
            q16b, k16b, v16b, b16, fp16p, aob, b0, CB);

        proj_gemm<<<dim3(CB * 2, 6), 256, 0, stream>>>(
            pw16, aob, proj_b, out, b0);
    }
}

// Round 11
// 396.487 us; speedup vs baseline: 2.4358x; 1.3057x over previous
//
#include <hip/hip_runtime.h>

#define B_   128
#define DIM_ 768
#define NH_  12
#define HD_  64
#define N_   256

using half8 = __attribute__((ext_vector_type(8))) _Float16;
using half4 = __attribute__((ext_vector_type(4))) _Float16;
using f32x4 = __attribute__((ext_vector_type(4))) float;
typedef unsigned short u16;
typedef unsigned int   u32;

// Staged (fragment-major) layout: per (tile, kstep) a 128row x 32k block is
// 512 chunks of 8 elems; chunk c = mtblock*64 + kgrp*16 + row16.
// Staging chunk c = tid + s*256 -> global src AND LDS dst lane-linear
// (global_load_lds form); frag read chunk = mtb*64 + lane -> conflict-free.

#define GLDS16(srcp, dstp) \
    __builtin_amdgcn_global_load_lds( \
        (const __attribute__((address_space(1))) void*)(srcp), \
        (__attribute__((address_space(3))) void*)(dstp), 16, 0, 0)

// ---------------------------------------------------------------------------
// bias16 = fp16(face_prior[h,n,m] + rel_table[relidx(n,m), h]) -> [NH, N, N]
// ---------------------------------------------------------------------------
__global__ __launch_bounds__(256) void bias16_kernel(
    const float* __restrict__ face_prior, const float* __restrict__ rel_table,
    _Float16* __restrict__ b16)
{
    int gid = blockIdx.x * 256 + threadIdx.x;    // over NH*N*N/2
    int idx = gid * 2;
    union { _Float16 s[2]; u32 u; } P;
    #pragma unroll
    for (int j = 0; j < 2; ++j) {
        int id = idx + j;
        int m = id & 255;
        int n = (id >> 8) & 255;
        int h = id >> 16;
        int rn = n >> 4, cn = n & 15;
        int rm = m >> 4, cm = m & 15;
        int ridx = (rn - rm + 15) * 31 + (cn - cm + 15);
        P.s[j] = (_Float16)(face_prior[id] + rel_table[ridx * NH_ + h]);
    }
    *(u32*)(b16 + idx) = P.u;
}

// ---------------------------------------------------------------------------
// generic fp32 -> fp16 linear conversion (8 elems/thread); for face_priors
// ---------------------------------------------------------------------------
__global__ __launch_bounds__(256) void conv_f32_f16(
    const float* __restrict__ in, _Float16* __restrict__ o16, int n8)
{
    int i = blockIdx.x * 256 + threadIdx.x;
    if (i >= n8) return;
    float4 a = *(const float4*)(in + (size_t)i * 8);
    float4 b = *(const float4*)(in + (size_t)i * 8 + 4);
    float v[8] = {a.x, a.y, a.z, a.w, b.x, b.y, b.z, b.w};
    union { _Float16 s[8]; uint4 q; } H;
    #pragma unroll
    for (int j = 0; j < 8; ++j) H.s[j] = (_Float16)v[j];
    *(uint4*)(o16 + (size_t)i * 8) = H.q;
}

// ---------------------------------------------------------------------------
// weights fp32 [T*128][768] -> fp16 staged [T][24][512][8]
// ---------------------------------------------------------------------------
__global__ __launch_bounds__(256) void conv_w_f16_staged(
    const float* __restrict__ in, _Float16* __restrict__ o16, int nchunk)
{
    int gid = blockIdx.x * 256 + threadIdx.x;
    if (gid >= nchunk) return;
    int t   = gid / 12288;          // 24*512
    int rem = gid % 12288;
    int ks  = rem >> 9;
    int c   = rem & 511;
    int mtb = c >> 6, kgrp = (c >> 4) & 3, r16 = c & 15;
    int srow = t * 128 + mtb * 16 + r16;
    int sk   = ks * 32 + kgrp * 8;
    float4 a = *(const float4*)(in + (size_t)srow * DIM_ + sk);
    float4 b = *(const float4*)(in + (size_t)srow * DIM_ + sk + 4);
    float v[8] = {a.x, a.y, a.z, a.w, b.x, b.y, b.z, b.w};
    union { _Float16 s[8]; uint4 q; } H;
    #pragma unroll
    for (int j = 0; j < 8; ++j) H.s[j] = (_Float16)v[j];
    *(uint4*)(o16 + (size_t)gid * 8) = H.q;
}

// ---------------------------------------------------------------------------
// x [B,768(k),256(n)] fp32 -> fp16 staged [B][2][24][512][8]
// ---------------------------------------------------------------------------
__global__ __launch_bounds__(256) void conv_transpose_x_f16(
    const float* __restrict__ x, _Float16* __restrict__ xa)
{
    __shared__ float T[64][65];
    const int b = blockIdx.z, k0 = blockIdx.x * 64, n0 = blockIdx.y * 64;
    const int t = threadIdx.x;
    const float* xb = x + (size_t)b * DIM_ * N_;
    {
        int nn = t & 63, kg = t >> 6;
        #pragma unroll
        for (int r = 0; r < 16; ++r) {
            int kk = r * 4 + kg;
            T[kk][nn] = xb[(size_t)(k0 + kk) * N_ + n0 + nn];
        }
    }
    __syncthreads();
    {
        int kk2 = (t & 31) * 2, ng = t >> 5;
        #pragma unroll
        for (int r = 0; r < 8; ++r) {
            int nn = r * 8 + ng;
            union { _Float16 s[2]; u32 u; } P;
            P.s[0] = (_Float16)T[kk2][nn];
            P.s[1] = (_Float16)T[kk2 + 1][nn];
            int n = n0 + nn, k = k0 + kk2;
            int half = n >> 7, mtb = (n >> 4) & 7, r16 = n & 15;
            int ks = k >> 5, kgrp = (k >> 3) & 3, koff = k & 7;
            size_t o = ((((size_t)b * 2 + half) * 24 + ks) * 512
                        + mtb * 64 + kgrp * 16 + r16) * 8 + koff;
            *(u32*)(xa + o) = P.u;
        }
    }
}

// ---------------------------------------------------------------------------
// QKV GEMM: fp16 1-term MFMA, staged layout + global_load_lds (m97 structure).
// Emits q16/k16/v16 fp16 slabs [cb,NH,N,HD]. grid (cb*2, 18)
// ---------------------------------------------------------------------------
__global__ __launch_bounds__(256) void qkv_gemm(
    const _Float16* __restrict__ w16, const _Float16* __restrict__ x16,
    const float* __restrict__ bvec,
    _Float16* __restrict__ q16, _Float16* __restrict__ k16,
    _Float16* __restrict__ v16,
    int b0, int cb)
{
    __shared__ __align__(16) _Float16 SW[4096], SX[4096];   // 16 KB

    const int tid  = threadIdx.x;
    const int lane = tid & 63;
    const int wv   = tid >> 6;
    const int wr   = wv >> 1;
    const int wc   = wv & 1;
    const int bx = blockIdx.x, by = blockIdx.y;
    const int bl = bx >> 1, half = bx & 1;
    const int b  = b0 + bl;

    const size_t wq0 = (size_t)by * 24 * 4096;
    const size_t xq0 = ((size_t)b * 2 + half) * 24 * 4096;

    f32x4 acc[4][4];
    #pragma unroll
    for (int i = 0; i < 4; ++i)
        #pragma unroll
        for (int j = 0; j < 4; ++j)
            acc[i][j] = (f32x4){0.f, 0.f, 0.f, 0.f};

    const int d0 = wv * 512;   // wave-uniform LDS base (elems)

    for (int ks = 0; ks < 24; ++ks) {
        const size_t wq = wq0 + (size_t)ks * 4096 + d0;
        const size_t xq = xq0 + (size_t)ks * 4096 + d0;
        #pragma unroll
        for (int s = 0; s < 2; ++s) {
            GLDS16(w16 + wq + s * 2048 + lane * 8, &SW[d0 + s * 2048]);
            GLDS16(x16 + xq + s * 2048 + lane * 8, &SX[d0 + s * 2048]);
        }
        __syncthreads();

        half8 ah[4];
        #pragma unroll
        for (int mt = 0; mt < 4; ++mt)
            ah[mt] = *(const half8*)&SW[((wr * 4 + mt) * 64 + lane) * 8];
        #pragma unroll
        for (int nt = 0; nt < 4; ++nt) {
            half8 bh = *(const half8*)&SX[((wc * 4 + nt) * 64 + lane) * 8];
            #pragma unroll
            for (int mt = 0; mt < 4; ++mt)
                acc[mt][nt] = __builtin_amdgcn_mfma_f32_16x16x32_f16(ah[mt], bh, acc[mt][nt], 0, 0, 0);
        }
        __syncthreads();
    }

    // C/D layout: col = lane&15 (n), row = (lane>>4)*4 + reg (oc)
    const int ocb = by * 128 + wr * 64 + (lane >> 4) * 4;
    const int nb  = half * 128 + wc * 64 + (lane & 15);

    #pragma unroll
    for (int mt = 0; mt < 4; ++mt) {
        int oc = ocb + mt * 16;
        float4 bv = *(const float4*)(bvec + oc);
        int which = oc / DIM_;            // uniform per block
        int r = oc - which * DIM_;
        int hh = r >> 6, d = r & 63;
        _Float16* slab = (which == 0) ? q16 : (which == 1) ? k16 : v16;
        size_t rowbase = ((size_t)bl * NH_ + hh) * (N_ * HD_) + d;
        #pragma unroll
        for (int nt = 0; nt < 4; ++nt) {
            int n = nb + nt * 16;
            union { _Float16 s[4]; uint2 u; } H;
            H.s[0] = (_Float16)(acc[mt][nt][0] + bv.x);
            H.s[1] = (_Float16)(acc[mt][nt][1] + bv.y);
            H.s[2] = (_Float16)(acc[mt][nt][2] + bv.z);
            H.s[3] = (_Float16)(acc[mt][nt][3] + bv.w);
            *(uint2*)(slab + rowbase + (size_t)n * HD_) = H.u;
        }
    }
}

// ---------------------------------------------------------------------------
// MFMA attention v3: stage full K[256][64] + Vt[64][256] ONCE (68KB LDS,
// 2 blocks/CU), then qt-OUTER loop with online softmax over two 128-kk
// chunks inside. Per-qt live state: oacc[4]+sacc[8]+bq[2] ~ 90 regs, nothing
// large lives across barriers -> no scratch spill (r9/r10: 84 VGPR + 314MB
// scratch writes from ch-outer structure holding oacc[4][4]+sacc across
// the whole kernel).
// ---------------------------------------------------------------------------
__global__ __launch_bounds__(256) void attn_mfma(
    const _Float16* __restrict__ q16, const _Float16* __restrict__ k16,
    const _Float16* __restrict__ v16,
    const _Float16* __restrict__ bias16, const _Float16* __restrict__ fpri16,
    _Float16* __restrict__ ao,
    int b0, int cb)
{
    extern __shared__ _Float16 ldsh[];
    _Float16* KL  = ldsh;                     // [256][64], idx = r*64 + (kc ^ ((r&7)<<3))
    _Float16* VtL = ldsh + 16384;             // [64][256], idx = d*256 + (kk ^ ((d&7)<<3))
    const int tid  = threadIdx.x;
    const int lane = tid & 63;
    const int wv   = tid >> 6;                // 0..3
    _Float16* PL = ldsh + 32768 + wv * 512;   // [16][32] per wave

    // m204 bijective XCD swizzle: co-locate same-b blocks (share fpri[b])
    const int nwg = cb * NH_;
    const int orig = blockIdx.x;
    const int xcd = orig & 7, loc = orig >> 3;
    const int qq = nwg >> 3, rr = nwg & 7;
    const int bh = (xcd < rr ? xcd * (qq + 1) : rr * (qq + 1) + (xcd - rr) * qq) + loc;

    const int bl = bh / NH_, h = bh % NH_;
    const int b  = b0 + bl;
    const size_t base = ((size_t)bl * NH_ + h) * (size_t)(N_ * HD_);

    const int l15 = lane & 15;
    const int lg  = lane >> 4;
    const int e   = (l15 & 3) << 1;           // PL swizzle

    // ---- stage K (full 256 rows, swizzled) ----
    #pragma unroll
    for (int s = 0; s < 8; ++s) {
        int idx = tid + s * 256;              // 0..2047
        int r = idx >> 3, kc = (idx & 7) * 8;
        *(half8*)&KL[r * 64 + (kc ^ ((r & 7) << 3))] =
            *(const half8*)(k16 + base + (size_t)r * 64 + kc);
    }
    // ---- stage V^T (full, gather; 128B-coalesced per wave instr) ----
    #pragma unroll
    for (int s = 0; s < 8; ++s) {
        int idx = tid + s * 256;
        int d = idx & 63, kkc = (idx >> 6) * 8;   // 0..248
        union { _Float16 sv[8]; half8 v; } t;
        #pragma unroll
        for (int j = 0; j < 8; ++j)
            t.sv[j] = v16[base + (size_t)(kkc + j) * 64 + d];
        *(half8*)&VtL[d * 256 + (kkc ^ ((d & 7) << 3))] = t.v;
    }
    __syncthreads();

    for (int qt = 0; qt < 4; ++qt) {
        const int qg = wv * 64 + qt * 16 + l15;
        const size_t qrow = base + (size_t)qg * 64;
        half8 bq[2];
        #pragma unroll
        for (int c = 0; c < 2; ++c)
            bq[c] = *(const half8*)(q16 + qrow + lg * 8 + c * 32);

        const _Float16* brow = bias16 + ((size_t)h * N_ + qg) * N_;
        const _Float16* frow = fpri16 + ((size_t)b * N_ + qg) * N_;

        float mrun = -1e30f, lrun = 0.f;
        f32x4 oacc[4];
        #pragma unroll
        for (int dt = 0; dt < 4; ++dt) oacc[dt] = (f32x4){0.f, 0.f, 0.f, 0.f};

        for (int ch = 0; ch < 2; ++ch) {
            f32x4 sacc[8];
            #pragma unroll
            for (int kt = 0; kt < 8; ++kt) {
                f32x4 sa = (f32x4){0.f, 0.f, 0.f, 0.f};
                int kr = ch * 128 + kt * 16 + l15;
                #pragma unroll
                for (int c = 0; c < 2; ++c) {
                    int kc = lg * 8 + c * 32;
                    half8 ah = *(const half8*)&KL[kr * 64 + (kc ^ ((kr & 7) << 3))];
                    sa = __builtin_amdgcn_mfma_f32_16x16x32_f16(ah, bq[c], sa, 0, 0, 0);
                }
                half4 bsv = *(const half4*)(brow + ch * 128 + kt * 16 + lg * 4);
                half4 fsv = *(const half4*)(frow + ch * 128 + kt * 16 + lg * 4);
                sacc[kt][0] = (sa[0] * 0.125f + (float)bsv[0]) * (float)fsv[0];
                sacc[kt][1] = (sa[1] * 0.125f + (float)bsv[1]) * (float)fsv[1];
                sacc[kt][2] = (sa[2] * 0.125f + (float)bsv[2]) * (float)fsv[2];
                sacc[kt][3] = (sa[3] * 0.125f + (float)bsv[3]) * (float)fsv[3];
            }

            // online softmax update (row qg: per-lane 32 vals + shfl 16/32)
            float cmax = -1e30f;
            #pragma unroll
            for (int kt = 0; kt < 8; ++kt)
                cmax = fmaxf(cmax, fmaxf(fmaxf(sacc[kt][0], sacc[kt][1]),
                                         fmaxf(sacc[kt][2], sacc[kt][3])));
            cmax = fmaxf(cmax, __shfl_xor(cmax, 16));
            cmax = fmaxf(cmax, __shfl_xor(cmax, 32));
            float mnew = fmaxf(mrun, cmax);
            float corr = __expf(mrun - mnew);
            mrun = mnew;
            float csum = 0.f;
            #pragma unroll
            for (int kt = 0; kt < 8; ++kt) {
                #pragma unroll
                for (int j = 0; j < 4; ++j) {
                    float p = __expf(sacc[kt][j] - mnew);
                    sacc[kt][j] = p;
                    csum += p;
                }
            }
            csum += __shfl_xor(csum, 16);
            csum += __shfl_xor(csum, 32);
            lrun = lrun * corr + csum;
            #pragma unroll
            for (int dt = 0; dt < 4; ++dt) {
                oacc[dt][0] *= corr; oacc[dt][1] *= corr;
                oacc[dt][2] *= corr; oacc[dt][3] *= corr;
            }

            // PV in 32-kk sub-chunks via per-wave PL buffer
            #pragma unroll
            for (int c2 = 0; c2 < 4; ++c2) {
                #pragma unroll
                for (int t = 0; t < 2; ++t) {
                    int kt = c2 * 2 + t;
                    union { _Float16 s[4]; uint2 u; } pw;
                    pw.s[0] = (_Float16)sacc[kt][0];
                    pw.s[1] = (_Float16)sacc[kt][1];
                    pw.s[2] = (_Float16)sacc[kt][2];
                    pw.s[3] = (_Float16)sacc[kt][3];
                    int u = (4 * t + lg) ^ e;
                    *(uint2*)&PL[l15 * 32 + u * 4] = pw.u;
                }
                half8 bp = *(const half8*)&PL[l15 * 32 + ((2 * lg) ^ e) * 4];
                int kc2 = ch * 128 + c2 * 32 + lg * 8;
                #pragma unroll
                for (int dt = 0; dt < 4; ++dt) {
                    int dr = dt * 16 + l15;
                    half8 av = *(const half8*)&VtL[dr * 256 + (kc2 ^ ((dr & 7) << 3))];
                    oacc[dt] = __builtin_amdgcn_mfma_f32_16x16x32_f16(av, bp, oacc[dt], 0, 0, 0);
                }
            }
        }

        // per-qt epilogue: scale by 1/l, emit fp16 staged [bl][2][24][512][8]
        float inv = 1.f / lrun;
        const int hf  = qg >> 7, mtb = (qg >> 4) & 7, r16 = qg & 15;
        #pragma unroll
        for (int dt = 0; dt < 4; ++dt) {
            int k = h * 64 + dt * 16 + lg * 4;
            int ks = k >> 5, kgrp = (k >> 3) & 3, koff = k & 7;
            size_t off = ((((size_t)(bl * 2 + hf) * 24 + ks) * 512)
                          + mtb * 64 + kgrp * 16 + r16) * 8 + koff;
            union { _Float16 s[4]; uint2 u; } H;
            #pragma unroll
            for (int j = 0; j < 4; ++j)
                H.s[j] = (_Float16)(oacc[dt][j] * inv);
            *(uint2*)(ao + off) = H.u;
        }
    }
}

// ---------------------------------------------------------------------------
// Proj GEMM, fp16 1-term, staged both sides + global_load_lds. grid (cb*2, 6)
// ---------------------------------------------------------------------------
__global__ __launch_bounds__(256) void proj_gemm(
    const _Float16* __restrict__ wst, const _Float16* __restrict__ ao,
    const float* __restrict__ bvec, float* __restrict__ outp,
    int b0)
{
    __shared__ __align__(16) _Float16 SW[4096], SX[4096];

    const int tid  = threadIdx.x;
    const int lane = tid & 63;
    const int wv   = tid >> 6;
    const int wr   = wv >> 1;
    const int wc   = wv & 1;
    const int bx = blockIdx.x, by = blockIdx.y;
    const int bl = bx >> 1, half = bx & 1;
    const int b  = b0 + bl;

    const size_t wq0 = (size_t)by * 24 * 4096;
    const size_t xq0 = ((size_t)bl * 2 + half) * 24 * 4096;

    f32x4 acc[4][4];
    #pragma unroll
    for (int i = 0; i < 4; ++i)
        #pragma unroll
        for (int j = 0; j < 4; ++j)
            acc[i][j] = (f32x4){0.f, 0.f, 0.f, 0.f};

    const int d0 = wv * 512;

    for (int ks = 0; ks < 24; ++ks) {
        const size_t wq = wq0 + (size_t)ks * 4096 + d0;
        const size_t xq = xq0 + (size_t)ks * 4096 + d0;
        #pragma unroll
        for (int s = 0; s < 2; ++s) {
            GLDS16(wst + wq + s * 2048 + lane * 8, &SW[d0 + s * 2048]);
            GLDS16(ao  + xq + s * 2048 + lane * 8, &SX[d0 + s * 2048]);
        }
        __syncthreads();

        half8 ah[4];
        #pragma unroll
        for (int mt = 0; mt < 4; ++mt)
            ah[mt] = *(const half8*)&SW[((wr * 4 + mt) * 64 + lane) * 8];
        #pragma unroll
        for (int nt = 0; nt < 4; ++nt) {
            half8 bh = *(const half8*)&SX[((wc * 4 + nt) * 64 + lane) * 8];
            #pragma unroll
            for (int mt = 0; mt < 4; ++mt)
                acc[mt][nt] = __builtin_amdgcn_mfma_f32_16x16x32_f16(ah[mt], bh, acc[mt][nt], 0, 0, 0);
        }
        __syncthreads();
    }

    const int ocb = by * 128 + wr * 64 + (lane >> 4) * 4;
    const int nb  = half * 128 + wc * 64 + (lane & 15);

    #pragma unroll
    for (int mt = 0; mt < 4; ++mt) {
        int oc = ocb + mt * 16;
        float4 bv = *(const float4*)(bvec + oc);
        float* obase = outp + (size_t)b * DIM_ * N_ + (size_t)oc * N_;
        #pragma unroll
        for (int nt = 0; nt < 4; ++nt) {
            int n = nb + nt * 16;
            obase[0 * N_ + n] = acc[mt][nt][0] + bv.x;
            obase[1 * N_ + n] = acc[mt][nt][1] + bv.y;
            obase[2 * N_ + n] = acc[mt][nt][2] + bv.z;
            obase[3 * N_ + n] = acc[mt][nt][3] + bv.w;
        }
    }
}

// ---------------------------------------------------------------------------
extern "C" void kernel_launch(void* const* d_in, const int* in_sizes, int n_in,
                              void* d_out, int out_size, void* d_ws, size_t ws_size,
                              hipStream_t stream)
{
    const float* x           = (const float*)d_in[0];
    const float* face_priors = (const float*)d_in[1];
    const float* qkv_w       = (const float*)d_in[2];
    const float* qkv_b       = (const float*)d_in[3];
    const float* rel_table   = (const float*)d_in[4];
    const float* face_prior  = (const float*)d_in[5];
    const float* proj_w      = (const float*)d_in[6];
    const float* proj_b      = (const float*)d_in[7];
    float* out = (float*)d_out;

    // persistent (fp16): bias16 1.57MB | fpri16 16.78MB | xa16 50.3MB
    //                  | qw16 3.54MB | pw16 1.18MB  = 73.4MB
    _Float16* b16   = (_Float16*)d_ws;
    _Float16* fp16p = b16 + (size_t)NH_ * N_ * N_;
    _Float16* xa16  = fp16p + (size_t)B_ * N_ * N_;
    _Float16* qw16  = xa16 + (size_t)B_ * N_ * DIM_;
    _Float16* pw16  = qw16 + (size_t)3 * DIM_ * DIM_;
    _Float16* cbase = pw16 + (size_t)DIM_ * DIM_;

    // per-batch chunk: q16/k16/v16/ao = 4 * cb * 393216 B
    const size_t PERSIST = 2ull * (NH_ * N_ * N_ + (size_t)B_ * N_ * N_
                         + (size_t)B_ * N_ * DIM_ + 4ull * DIM_ * DIM_);
    int CB = 1;
    const int cands[] = {128, 64, 32, 16, 8, 4, 2, 1};
    for (int ci = 0; ci < 8; ++ci) {
        if (PERSIST + (size_t)cands[ci] * 1572864ull <= ws_size) { CB = cands[ci]; break; }
    }
    const size_t SL = (size_t)CB * NH_ * N_ * HD_;
    _Float16* q16b = cbase;
    _Float16* k16b = q16b + SL;
    _Float16* v16b = k16b + SL;
    _Float16* aob  = v16b + SL;

    hipFuncSetAttribute((const void*)attn_mfma,
                        hipFuncAttributeMaxDynamicSharedMemorySize, 69632);

    bias16_kernel<<<(NH_ * N_ * N_ / 2) / 256, 256, 0, stream>>>(face_prior, rel_table, b16);
    conv_f32_f16<<<((B_ * N_ * N_ / 8) + 255) / 256, 256, 0, stream>>>(face_priors, fp16p, B_ * N_ * N_ / 8);
    conv_w_f16_staged<<<(18 * 12288 + 255) / 256, 256, 0, stream>>>(qkv_w, qw16, 18 * 12288);
    conv_w_f16_staged<<<(6 * 12288 + 255) / 256, 256, 0, stream>>>(proj_w, pw16, 6 * 12288);
    conv_transpose_x_f16<<<dim3(12, 4, B_), 256, 0, stream>>>(x, xa16);

    for (int b0 = 0; b0 < B_; b0 += CB) {
        qkv_gemm<<<dim3(CB * 2, 18), 256, 0, stream>>>(
            qw16, xa16, qkv_b, q16b, k16b, v16b, b0, CB);

        attn_mfma<<<CB * NH_, 256, 69632, stream>>>(
            q16b, k16b, v16b, b16, fp16p, aob, b0, CB);

        proj_gemm<<<dim3(CB * 2, 6), 256, 0, stream>>>(
            pw16, aob, proj_b, out, b0);
    }
}

// Round 12
// 386.090 us; speedup vs baseline: 2.5014x; 1.0269x over previous
//
#include <hip/hip_runtime.h>

#define B_   128
#define DIM_ 768
#define NH_  12
#define HD_  64
#define N_   256

using half8 = __attribute__((ext_vector_type(8))) _Float16;
using half4 = __attribute__((ext_vector_type(4))) _Float16;
using f32x4 = __attribute__((ext_vector_type(4))) float;
typedef unsigned short u16;
typedef unsigned int   u32;

// Staged (fragment-major) layout: per (tile, kstep) a 128row x 32k block is
// 512 chunks of 8 elems; chunk c = mtblock*64 + kgrp*16 + row16.
// Staging chunk c = tid + s*256 -> global src AND LDS dst lane-linear
// (global_load_lds form); frag read chunk = mtb*64 + lane -> conflict-free.

#define GLDS16(srcp, dstp) \
    __builtin_amdgcn_global_load_lds( \
        (const __attribute__((address_space(1))) void*)(srcp), \
        (__attribute__((address_space(3))) void*)(dstp), 16, 0, 0)

// m204 bijective XCD swizzle: orig -> wg such that each XCD gets a
// contiguous wg chunk (assumes round-robin dispatch orig%8 -> XCD).
__device__ __forceinline__ int xcd_chunked(int orig, int nwg) {
    int xcd = orig & 7, loc = orig >> 3;
    int qq = nwg >> 3, rr = nwg & 7;
    return (xcd < rr ? xcd * (qq + 1) : rr * (qq + 1) + (xcd - rr) * qq) + loc;
}

// ---------------------------------------------------------------------------
// bias16 = fp16(face_prior[h,n,m] + rel_table[relidx(n,m), h]) -> [NH, N, N]
// ---------------------------------------------------------------------------
__global__ __launch_bounds__(256) void bias16_kernel(
    const float* __restrict__ face_prior, const float* __restrict__ rel_table,
    _Float16* __restrict__ b16)
{
    int gid = blockIdx.x * 256 + threadIdx.x;    // over NH*N*N/2
    int idx = gid * 2;
    union { _Float16 s[2]; u32 u; } P;
    #pragma unroll
    for (int j = 0; j < 2; ++j) {
        int id = idx + j;
        int m = id & 255;
        int n = (id >> 8) & 255;
        int h = id >> 16;
        int rn = n >> 4, cn = n & 15;
        int rm = m >> 4, cm = m & 15;
        int ridx = (rn - rm + 15) * 31 + (cn - cm + 15);
        P.s[j] = (_Float16)(face_prior[id] + rel_table[ridx * NH_ + h]);
    }
    *(u32*)(b16 + idx) = P.u;
}

// ---------------------------------------------------------------------------
// generic fp32 -> fp16 linear conversion (8 elems/thread); for face_priors
// ---------------------------------------------------------------------------
__global__ __launch_bounds__(256) void conv_f32_f16(
    const float* __restrict__ in, _Float16* __restrict__ o16, int n8)
{
    int i = blockIdx.x * 256 + threadIdx.x;
    if (i >= n8) return;
    float4 a = *(const float4*)(in + (size_t)i * 8);
    float4 b = *(const float4*)(in + (size_t)i * 8 + 4);
    float v[8] = {a.x, a.y, a.z, a.w, b.x, b.y, b.z, b.w};
    union { _Float16 s[8]; uint4 q; } H;
    #pragma unroll
    for (int j = 0; j < 8; ++j) H.s[j] = (_Float16)v[j];
    *(uint4*)(o16 + (size_t)i * 8) = H.q;
}

// ---------------------------------------------------------------------------
// weights fp32 [T*128][768] -> fp16 staged [T][24][512][8]
// ---------------------------------------------------------------------------
__global__ __launch_bounds__(256) void conv_w_f16_staged(
    const float* __restrict__ in, _Float16* __restrict__ o16, int nchunk)
{
    int gid = blockIdx.x * 256 + threadIdx.x;
    if (gid >= nchunk) return;
    int t   = gid / 12288;          // 24*512
    int rem = gid % 12288;
    int ks  = rem >> 9;
    int c   = rem & 511;
    int mtb = c >> 6, kgrp = (c >> 4) & 3, r16 = c & 15;
    int srow = t * 128 + mtb * 16 + r16;
    int sk   = ks * 32 + kgrp * 8;
    float4 a = *(const float4*)(in + (size_t)srow * DIM_ + sk);
    float4 b = *(const float4*)(in + (size_t)srow * DIM_ + sk + 4);
    float v[8] = {a.x, a.y, a.z, a.w, b.x, b.y, b.z, b.w};
    union { _Float16 s[8]; uint4 q; } H;
    #pragma unroll
    for (int j = 0; j < 8; ++j) H.s[j] = (_Float16)v[j];
    *(uint4*)(o16 + (size_t)gid * 8) = H.q;
}

// ---------------------------------------------------------------------------
// x [B,768(k),256(n)] fp32 -> fp16 staged [B][2][24][512][8]
// ---------------------------------------------------------------------------
__global__ __launch_bounds__(256) void conv_transpose_x_f16(
    const float* __restrict__ x, _Float16* __restrict__ xa)
{
    __shared__ float T[64][65];
    const int b = blockIdx.z, k0 = blockIdx.x * 64, n0 = blockIdx.y * 64;
    const int t = threadIdx.x;
    const float* xb = x + (size_t)b * DIM_ * N_;
    {
        int nn = t & 63, kg = t >> 6;
        #pragma unroll
        for (int r = 0; r < 16; ++r) {
            int kk = r * 4 + kg;
            T[kk][nn] = xb[(size_t)(k0 + kk) * N_ + n0 + nn];
        }
    }
    __syncthreads();
    {
        int kk2 = (t & 31) * 2, ng = t >> 5;
        #pragma unroll
        for (int r = 0; r < 8; ++r) {
            int nn = r * 8 + ng;
            union { _Float16 s[2]; u32 u; } P;
            P.s[0] = (_Float16)T[kk2][nn];
            P.s[1] = (_Float16)T[kk2 + 1][nn];
            int n = n0 + nn, k = k0 + kk2;
            int half = n >> 7, mtb = (n >> 4) & 7, r16 = n & 15;
            int ks = k >> 5, kgrp = (k >> 3) & 3, koff = k & 7;
            size_t o = ((((size_t)b * 2 + half) * 24 + ks) * 512
                        + mtb * 64 + kgrp * 16 + r16) * 8 + koff;
            *(u32*)(xa + o) = P.u;
        }
    }
}

// ---------------------------------------------------------------------------
// QKV GEMM: fp16 1-term MFMA, staged layout + global_load_lds (m97 structure)
// + XCD-chunked 1D grid (by fastest within an XCD chunk -> X tile L2-resident,
// shrinking the vmcnt-drain stall). grid: cb*36 blocks.
// ---------------------------------------------------------------------------
__global__ __launch_bounds__(256) void qkv_gemm(
    const _Float16* __restrict__ w16, const _Float16* __restrict__ x16,
    const float* __restrict__ bvec,
    _Float16* __restrict__ q16, _Float16* __restrict__ k16,
    _Float16* __restrict__ v16,
    int b0, int cb)
{
    __shared__ __align__(16) _Float16 SW[4096], SX[4096];   // 16 KB

    const int tid  = threadIdx.x;
    const int lane = tid & 63;
    const int wv   = tid >> 6;
    const int wr   = wv >> 1;
    const int wc   = wv & 1;

    const int wg = xcd_chunked(blockIdx.x, cb * 36);
    const int by = wg % 18;            // fast: same X tile across by
    const int bx = wg / 18;
    const int bl = bx >> 1, half = bx & 1;
    const int b  = b0 + bl;

    const size_t wq0 = (size_t)by * 24 * 4096;
    const size_t xq0 = ((size_t)b * 2 + half) * 24 * 4096;

    f32x4 acc[4][4];
    #pragma unroll
    for (int i = 0; i < 4; ++i)
        #pragma unroll
        for (int j = 0; j < 4; ++j)
            acc[i][j] = (f32x4){0.f, 0.f, 0.f, 0.f};

    const int d0 = wv * 512;   // wave-uniform LDS base (elems)

    for (int ks = 0; ks < 24; ++ks) {
        const size_t wq = wq0 + (size_t)ks * 4096 + d0;
        const size_t xq = xq0 + (size_t)ks * 4096 + d0;
        #pragma unroll
        for (int s = 0; s < 2; ++s) {
            GLDS16(w16 + wq + s * 2048 + lane * 8, &SW[d0 + s * 2048]);
            GLDS16(x16 + xq + s * 2048 + lane * 8, &SX[d0 + s * 2048]);
        }
        __syncthreads();

        half8 ah[4];
        #pragma unroll
        for (int mt = 0; mt < 4; ++mt)
            ah[mt] = *(const half8*)&SW[((wr * 4 + mt) * 64 + lane) * 8];
        #pragma unroll
        for (int nt = 0; nt < 4; ++nt) {
            half8 bh = *(const half8*)&SX[((wc * 4 + nt) * 64 + lane) * 8];
            #pragma unroll
            for (int mt = 0; mt < 4; ++mt)
                acc[mt][nt] = __builtin_amdgcn_mfma_f32_16x16x32_f16(ah[mt], bh, acc[mt][nt], 0, 0, 0);
        }
        __syncthreads();
    }

    // C/D layout: col = lane&15 (n), row = (lane>>4)*4 + reg (oc)
    const int ocb = by * 128 + wr * 64 + (lane >> 4) * 4;
    const int nb  = half * 128 + wc * 64 + (lane & 15);

    #pragma unroll
    for (int mt = 0; mt < 4; ++mt) {
        int oc = ocb + mt * 16;
        float4 bv = *(const float4*)(bvec + oc);
        int which = oc / DIM_;            // uniform per block
        int r = oc - which * DIM_;
        int hh = r >> 6, d = r & 63;
        _Float16* slab = (which == 0) ? q16 : (which == 1) ? k16 : v16;
        size_t rowbase = ((size_t)bl * NH_ + hh) * (N_ * HD_) + d;
        #pragma unroll
        for (int nt = 0; nt < 4; ++nt) {
            int n = nb + nt * 16;
            union { _Float16 s[4]; uint2 u; } H;
            H.s[0] = (_Float16)(acc[mt][nt][0] + bv.x);
            H.s[1] = (_Float16)(acc[mt][nt][1] + bv.y);
            H.s[2] = (_Float16)(acc[mt][nt][2] + bv.z);
            H.s[3] = (_Float16)(acc[mt][nt][3] + bv.w);
            *(uint2*)(slab + rowbase + (size_t)n * HD_) = H.u;
        }
    }
}

// ---------------------------------------------------------------------------
// MFMA attention v3 (unchanged from r11): full K+Vt staged once (68KB LDS,
// 2 blocks/CU), qt-outer loop, online softmax inside -> no scratch spill.
// ---------------------------------------------------------------------------
__global__ __launch_bounds__(256) void attn_mfma(
    const _Float16* __restrict__ q16, const _Float16* __restrict__ k16,
    const _Float16* __restrict__ v16,
    const _Float16* __restrict__ bias16, const _Float16* __restrict__ fpri16,
    _Float16* __restrict__ ao,
    int b0, int cb)
{
    extern __shared__ _Float16 ldsh[];
    _Float16* KL  = ldsh;                     // [256][64], idx = r*64 + (kc ^ ((r&7)<<3))
    _Float16* VtL = ldsh + 16384;             // [64][256], idx = d*256 + (kk ^ ((d&7)<<3))
    const int tid  = threadIdx.x;
    const int lane = tid & 63;
    const int wv   = tid >> 6;                // 0..3
    _Float16* PL = ldsh + 32768 + wv * 512;   // [16][32] per wave

    const int bh = xcd_chunked(blockIdx.x, cb * NH_);
    const int bl = bh / NH_, h = bh % NH_;
    const int b  = b0 + bl;
    const size_t base = ((size_t)bl * NH_ + h) * (size_t)(N_ * HD_);

    const int l15 = lane & 15;
    const int lg  = lane >> 4;
    const int e   = (l15 & 3) << 1;           // PL swizzle

    // ---- stage K (full 256 rows, swizzled) ----
    #pragma unroll
    for (int s = 0; s < 8; ++s) {
        int idx = tid + s * 256;              // 0..2047
        int r = idx >> 3, kc = (idx & 7) * 8;
        *(half8*)&KL[r * 64 + (kc ^ ((r & 7) << 3))] =
            *(const half8*)(k16 + base + (size_t)r * 64 + kc);
    }
    // ---- stage V^T (full, gather; 128B-coalesced per wave instr) ----
    #pragma unroll
    for (int s = 0; s < 8; ++s) {
        int idx = tid + s * 256;
        int d = idx & 63, kkc = (idx >> 6) * 8;   // 0..248
        union { _Float16 sv[8]; half8 v; } t;
        #pragma unroll
        for (int j = 0; j < 8; ++j)
            t.sv[j] = v16[base + (size_t)(kkc + j) * 64 + d];
        *(half8*)&VtL[d * 256 + (kkc ^ ((d & 7) << 3))] = t.v;
    }
    __syncthreads();

    for (int qt = 0; qt < 4; ++qt) {
        const int qg = wv * 64 + qt * 16 + l15;
        const size_t qrow = base + (size_t)qg * 64;
        half8 bq[2];
        #pragma unroll
        for (int c = 0; c < 2; ++c)
            bq[c] = *(const half8*)(q16 + qrow + lg * 8 + c * 32);

        const _Float16* brow = bias16 + ((size_t)h * N_ + qg) * N_;
        const _Float16* frow = fpri16 + ((size_t)b * N_ + qg) * N_;

        float mrun = -1e30f, lrun = 0.f;
        f32x4 oacc[4];
        #pragma unroll
        for (int dt = 0; dt < 4; ++dt) oacc[dt] = (f32x4){0.f, 0.f, 0.f, 0.f};

        for (int ch = 0; ch < 2; ++ch) {
            f32x4 sacc[8];
            #pragma unroll
            for (int kt = 0; kt < 8; ++kt) {
                f32x4 sa = (f32x4){0.f, 0.f, 0.f, 0.f};
                int kr = ch * 128 + kt * 16 + l15;
                #pragma unroll
                for (int c = 0; c < 2; ++c) {
                    int kc = lg * 8 + c * 32;
                    half8 ah = *(const half8*)&KL[kr * 64 + (kc ^ ((kr & 7) << 3))];
                    sa = __builtin_amdgcn_mfma_f32_16x16x32_f16(ah, bq[c], sa, 0, 0, 0);
                }
                half4 bsv = *(const half4*)(brow + ch * 128 + kt * 16 + lg * 4);
                half4 fsv = *(const half4*)(frow + ch * 128 + kt * 16 + lg * 4);
                sacc[kt][0] = (sa[0] * 0.125f + (float)bsv[0]) * (float)fsv[0];
                sacc[kt][1] = (sa[1] * 0.125f + (float)bsv[1]) * (float)fsv[1];
                sacc[kt][2] = (sa[2] * 0.125f + (float)bsv[2]) * (float)fsv[2];
                sacc[kt][3] = (sa[3] * 0.125f + (float)bsv[3]) * (float)fsv[3];
            }

            // online softmax update (row qg: per-lane 32 vals + shfl 16/32)
            float cmax = -1e30f;
            #pragma unroll
            for (int kt = 0; kt < 8; ++kt)
                cmax = fmaxf(cmax, fmaxf(fmaxf(sacc[kt][0], sacc[kt][1]),
                                         fmaxf(sacc[kt][2], sacc[kt][3])));
            cmax = fmaxf(cmax, __shfl_xor(cmax, 16));
            cmax = fmaxf(cmax, __shfl_xor(cmax, 32));
            float mnew = fmaxf(mrun, cmax);
            float corr = __expf(mrun - mnew);
            mrun = mnew;
            float csum = 0.f;
            #pragma unroll
            for (int kt = 0; kt < 8; ++kt) {
                #pragma unroll
                for (int j = 0; j < 4; ++j) {
                    float p = __expf(sacc[kt][j] - mnew);
                    sacc[kt][j] = p;
                    csum += p;
                }
            }
            csum += __shfl_xor(csum, 16);
            csum += __shfl_xor(csum, 32);
            lrun = lrun * corr + csum;
            #pragma unroll
            for (int dt = 0; dt < 4; ++dt) {
                oacc[dt][0] *= corr; oacc[dt][1] *= corr;
                oacc[dt][2] *= corr; oacc[dt][3] *= corr;
            }

            // PV in 32-kk sub-chunks via per-wave PL buffer
            #pragma unroll
            for (int c2 = 0; c2 < 4; ++c2) {
                #pragma unroll
                for (int t = 0; t < 2; ++t) {
                    int kt = c2 * 2 + t;
                    union { _Float16 s[4]; uint2 u; } pw;
                    pw.s[0] = (_Float16)sacc[kt][0];
                    pw.s[1] = (_Float16)sacc[kt][1];
                    pw.s[2] = (_Float16)sacc[kt][2];
                    pw.s[3] = (_Float16)sacc[kt][3];
                    int u = (4 * t + lg) ^ e;
                    *(uint2*)&PL[l15 * 32 + u * 4] = pw.u;
                }
                half8 bp = *(const half8*)&PL[l15 * 32 + ((2 * lg) ^ e) * 4];
                int kc2 = ch * 128 + c2 * 32 + lg * 8;
                #pragma unroll
                for (int dt = 0; dt < 4; ++dt) {
                    int dr = dt * 16 + l15;
                    half8 av = *(const half8*)&VtL[dr * 256 + (kc2 ^ ((dr & 7) << 3))];
                    oacc[dt] = __builtin_amdgcn_mfma_f32_16x16x32_f16(av, bp, oacc[dt], 0, 0, 0);
                }
            }
        }

        // per-qt epilogue: scale by 1/l, emit fp16 staged [bl][2][24][512][8]
        float inv = 1.f / lrun;
        const int hf  = qg >> 7, mtb = (qg >> 4) & 7, r16 = qg & 15;
        #pragma unroll
        for (int dt = 0; dt < 4; ++dt) {
            int k = h * 64 + dt * 16 + lg * 4;
            int ks = k >> 5, kgrp = (k >> 3) & 3, koff = k & 7;
            size_t off = ((((size_t)(bl * 2 + hf) * 24 + ks) * 512)
                          + mtb * 64 + kgrp * 16 + r16) * 8 + koff;
            union { _Float16 s[4]; uint2 u; } H;
            #pragma unroll
            for (int j = 0; j < 4; ++j)
                H.s[j] = (_Float16)(oacc[dt][j] * inv);
            *(uint2*)(ao + off) = H.u;
        }
    }
}

// ---------------------------------------------------------------------------
// Proj GEMM, fp16 1-term, staged both sides + global_load_lds + XCD-chunked
// 1D grid (by fastest). grid: cb*12 blocks.
// ---------------------------------------------------------------------------
__global__ __launch_bounds__(256) void proj_gemm(
    const _Float16* __restrict__ wst, const _Float16* __restrict__ ao,
    const float* __restrict__ bvec, float* __restrict__ outp,
    int b0, int cb)
{
    __shared__ __align__(16) _Float16 SW[4096], SX[4096];

    const int tid  = threadIdx.x;
    const int lane = tid & 63;
    const int wv   = tid >> 6;
    const int wr   = wv >> 1;
    const int wc   = wv & 1;

    const int wg = xcd_chunked(blockIdx.x, cb * 12);
    const int by = wg % 6;             // fast: same X tile across by
    const int bx = wg / 6;
    const int bl = bx >> 1, half = bx & 1;
    const int b  = b0 + bl;

    const size_t wq0 = (size_t)by * 24 * 4096;
    const size_t xq0 = ((size_t)bl * 2 + half) * 24 * 4096;

    f32x4 acc[4][4];
    #pragma unroll
    for (int i = 0; i < 4; ++i)
        #pragma unroll
        for (int j = 0; j < 4; ++j)
            acc[i][j] = (f32x4){0.f, 0.f, 0.f, 0.f};

    const int d0 = wv * 512;

    for (int ks = 0; ks < 24; ++ks) {
        const size_t wq = wq0 + (size_t)ks * 4096 + d0;
        const size_t xq = xq0 + (size_t)ks * 4096 + d0;
        #pragma unroll
        for (int s = 0; s < 2; ++s) {
            GLDS16(wst + wq + s * 2048 + lane * 8, &SW[d0 + s * 2048]);
            GLDS16(ao  + xq + s * 2048 + lane * 8, &SX[d0 + s * 2048]);
        }
        __syncthreads();

        half8 ah[4];
        #pragma unroll
        for (int mt = 0; mt < 4; ++mt)
            ah[mt] = *(const half8*)&SW[((wr * 4 + mt) * 64 + lane) * 8];
        #pragma unroll
        for (int nt = 0; nt < 4; ++nt) {
            half8 bh = *(const half8*)&SX[((wc * 4 + nt) * 64 + lane) * 8];
            #pragma unroll
            for (int mt = 0; mt < 4; ++mt)
                acc[mt][nt] = __builtin_amdgcn_mfma_f32_16x16x32_f16(ah[mt], bh, acc[mt][nt], 0, 0, 0);
        }
        __syncthreads();
    }

    const int ocb = by * 128 + wr * 64 + (lane >> 4) * 4;
    const int nb  = half * 128 + wc * 64 + (lane & 15);

    #pragma unroll
    for (int mt = 0; mt < 4; ++mt) {
        int oc = ocb + mt * 16;
        float4 bv = *(const float4*)(bvec + oc);
        float* obase = outp + (size_t)b * DIM_ * N_ + (size_t)oc * N_;
        #pragma unroll
        for (int nt = 0; nt < 4; ++nt) {
            int n = nb + nt * 16;
            obase[0 * N_ + n] = acc[mt][nt][0] + bv.x;
            obase[1 * N_ + n] = acc[mt][nt][1] + bv.y;
            obase[2 * N_ + n] = acc[mt][nt][2] + bv.z;
            obase[3 * N_ + n] = acc[mt][nt][3] + bv.w;
        }
    }
}

// ---------------------------------------------------------------------------
extern "C" void kernel_launch(void* const* d_in, const int* in_sizes, int n_in,
                              void* d_out, int out_size, void* d_ws, size_t ws_size,
                              hipStream_t stream)
{
    const float* x           = (const float*)d_in[0];
    const float* face_priors = (const float*)d_in[1];
    const float* qkv_w       = (const float*)d_in[2];
    const float* qkv_b       = (const float*)d_in[3];
    const float* rel_table   = (const float*)d_in[4];
    const float* face_prior  = (const float*)d_in[5];
    const float* proj_w      = (const float*)d_in[6];
    const float* proj_b      = (const float*)d_in[7];
    float* out = (float*)d_out;

    // persistent (fp16): bias16 1.57MB | fpri16 16.78MB | xa16 50.3MB
    //                  | qw16 3.54MB | pw16 1.18MB  = 73.4MB
    _Float16* b16   = (_Float16*)d_ws;
    _Float16* fp16p = b16 + (size_t)NH_ * N_ * N_;
    _Float16* xa16  = fp16p + (size_t)B_ * N_ * N_;
    _Float16* qw16  = xa16 + (size_t)B_ * N_ * DIM_;
    _Float16* pw16  = qw16 + (size_t)3 * DIM_ * DIM_;
    _Float16* cbase = pw16 + (size_t)DIM_ * DIM_;

    // per-batch chunk: q16/k16/v16/ao = 4 * cb * 393216 B
    const size_t PERSIST = 2ull * (NH_ * N_ * N_ + (size_t)B_ * N_ * N_
                         + (size_t)B_ * N_ * DIM_ + 4ull * DIM_ * DIM_);
    int CB = 1;
    const int cands[] = {128, 64, 32, 16, 8, 4, 2, 1};
    for (int ci = 0; ci < 8; ++ci) {
        if (PERSIST + (size_t)cands[ci] * 1572864ull <= ws_size) { CB = cands[ci]; break; }
    }
    const size_t SL = (size_t)CB * NH_ * N_ * HD_;
    _Float16* q16b = cbase;
    _Float16* k16b = q16b + SL;
    _Float16* v16b = k16b + SL;
    _Float16* aob  = v16b + SL;

    hipFuncSetAttribute((const void*)attn_mfma,
                        hipFuncAttributeMaxDynamicSharedMemorySize, 69632);

    bias16_kernel<<<(NH_ * N_ * N_ / 2) / 256, 256, 0, stream>>>(face_prior, rel_table, b16);
    conv_f32_f16<<<((B_ * N_ * N_ / 8) + 255) / 256, 256, 0, stream>>>(face_priors, fp16p, B_ * N_ * N_ / 8);
    conv_w_f16_staged<<<(18 * 12288 + 255) / 256, 256, 0, stream>>>(qkv_w, qw16, 18 * 12288);
    conv_w_f16_staged<<<(6 * 12288 + 255) / 256, 256, 0, stream>>>(proj_w, pw16, 6 * 12288);
    conv_transpose_x_f16<<<dim3(12, 4, B_), 256, 0, stream>>>(x, xa16);

    for (int b0 = 0; b0 < B_; b0 += CB) {
        qkv_gemm<<<CB * 36, 256, 0, stream>>>(
            qw16, xa16, qkv_b, q16b, k16b, v16b, b0, CB);

        attn_mfma<<<CB * NH_, 256, 69632, stream>>>(
            q16b, k16b, v16b, b16, fp16p, aob, b0, CB);

        proj_gemm<<<CB * 12, 256, 0, stream>>>(
            pw16, aob, proj_b, out, b0, CB);
    }
}